// Round 6
// baseline (11124.072 us; speedup 1.0000x reference)
//
#include <hip/hip_runtime.h>
#include <cstdint>

typedef unsigned long long u64;

static __device__ __forceinline__ float leakyf(float v) { return v >= 0.f ? v : 0.2f * v; }

// ------------------------------------------------------------------
// Pack [M,3] positions into float4(x,y,z,|p|^2). ss association (x*x+y*y)+z*z
// must match the query-side qq usage in knn/three_nn.
__global__ void pack_kernel(const float* __restrict__ pos, int total, float4* __restrict__ out)
{
  int i = blockIdx.x * 256 + threadIdx.x;
  if (i >= total) return;
  float x = pos[i*3+0], y = pos[i*3+1], z = pos[i*3+2];
  out[i] = make_float4(x, y, z, (x*x + y*y) + z*z);
}

// ------------------------------------------------------------------
// DPP wave64 reductions (rocPRIM pattern): row_shr 1/2/4/8 + row_bcast15/31.
template<int CTRL>
static __device__ __forceinline__ float dpp_max_f_step(float x)
{
  int y = __builtin_amdgcn_update_dpp(__float_as_int(x), __float_as_int(x), CTRL, 0xF, 0xF, false);
  return fmaxf(x, __int_as_float(y));
}
static __device__ __forceinline__ float wave64_max_f(float x)
{
  x = dpp_max_f_step<0x111>(x);  // row_shr:1
  x = dpp_max_f_step<0x112>(x);  // row_shr:2
  x = dpp_max_f_step<0x114>(x);  // row_shr:4
  x = dpp_max_f_step<0x118>(x);  // row_shr:8
  x = dpp_max_f_step<0x142>(x);  // row_bcast:15
  x = dpp_max_f_step<0x143>(x);  // row_bcast:31
  return __int_as_float(__builtin_amdgcn_readlane(__float_as_int(x), 63));
}
template<int CTRL>
static __device__ __forceinline__ unsigned dpp_max_u_step(unsigned x)
{
  unsigned y = (unsigned)__builtin_amdgcn_update_dpp((int)x, (int)x, CTRL, 0xF, 0xF, false);
  return x > y ? x : y;
}
static __device__ __forceinline__ unsigned wave64_max_u(unsigned x)
{
  x = dpp_max_u_step<0x111>(x);
  x = dpp_max_u_step<0x112>(x);
  x = dpp_max_u_step<0x114>(x);
  x = dpp_max_u_step<0x118>(x);
  x = dpp_max_u_step<0x142>(x);
  x = dpp_max_u_step<0x143>(x);
  return (unsigned)__builtin_amdgcn_readlane((int)x, 63);
}

// ------------------------------------------------------------------
static __device__ __forceinline__ unsigned part1by2(unsigned v)
{
  v &= 0x3FFu;
  v = (v | (v << 16)) & 0x030000FFu;
  v = (v | (v << 8))  & 0x0300F00Fu;
  v = (v | (v << 4))  & 0x030C30C3u;
  v = (v | (v << 2))  & 0x09249249u;
  return v;
}

// FPS prep: Morton bitonic sort; emits ONLY the sorted original-index array.
// Correctness of FPS needs just "sord is a permutation" (bitonic swaps guarantee);
// Morton quality affects pruning speed only.
template<int N>
__global__ __launch_bounds__(512) void fps_prep_kernel(const float* __restrict__ pos,
                                                       unsigned* __restrict__ sordg)
{
  const int b = blockIdx.x;
  const float* P = pos + (size_t)b * N * 3;
  unsigned* SORD = sordg + (size_t)b * N;

  __shared__ u64 skey[N];
  __shared__ float sred[512];
  const int t = threadIdx.x;

  float mn[3] = {3.4e38f, 3.4e38f, 3.4e38f};
  float mx[3] = {-3.4e38f, -3.4e38f, -3.4e38f};
  for (int i = t; i < N; i += 512) {
    float c3[3] = {P[i*3], P[i*3+1], P[i*3+2]};
#pragma unroll
    for (int a = 0; a < 3; ++a) { mn[a] = fminf(mn[a], c3[a]); mx[a] = fmaxf(mx[a], c3[a]); }
  }
  float bmin[3], inv[3];
  for (int a = 0; a < 3; ++a) {
    sred[t] = mn[a]; __syncthreads();
    for (int s = 256; s > 0; s >>= 1) { if (t < s) sred[t] = fminf(sred[t], sred[t+s]); __syncthreads(); }
    bmin[a] = sred[0]; __syncthreads();
    sred[t] = mx[a]; __syncthreads();
    for (int s = 256; s > 0; s >>= 1) { if (t < s) sred[t] = fmaxf(sred[t], sred[t+s]); __syncthreads(); }
    float bmax = sred[0]; __syncthreads();
    inv[a] = 1023.0f / fmaxf(bmax - bmin[a], 1e-20f);
  }
  for (int i = t; i < N; i += 512) {
    float x = P[i*3], y = P[i*3+1], z = P[i*3+2];
    unsigned cx = (unsigned)fminf(fmaxf((x - bmin[0]) * inv[0], 0.f), 1023.f);
    unsigned cy = (unsigned)fminf(fmaxf((y - bmin[1]) * inv[1], 0.f), 1023.f);
    unsigned cz = (unsigned)fminf(fmaxf((z - bmin[2]) * inv[2], 0.f), 1023.f);
    unsigned code = part1by2(cx) | (part1by2(cy) << 1) | (part1by2(cz) << 2);
    skey[i] = ((u64)code << 32) | (unsigned)i;
  }
  __syncthreads();
  for (int k = 2; k <= N; k <<= 1)
    for (int j = k >> 1; j > 0; j >>= 1) {
      for (int i = t; i < N; i += 512) {
        int ixj = i ^ j;
        if (ixj > i) {
          u64 a = skey[i], c = skey[ixj];
          if ((a > c) == ((i & k) == 0)) { skey[i] = c; skey[ixj] = a; }
        }
      }
      __syncthreads();
    }
  for (int i = t; i < N; i += 512)
    SORD[i] = (unsigned)(skey[i] & 0xFFFFFFFFull);
}

// ------------------------------------------------------------------
// Furthest point sampling, exact, with PER-THREAD REGISTER PRUNING.
// Thread owns NPT Morton-consecutive points (coords/dist/iv in registers) plus
// a bounding sphere (gc, r) and cached lexmax (bd, biv) of its dists.
// Per iter: if |c-gc|^2 >= (sqrt(bd)+r)^2 * margin, then provably every new
// distance >= bd >= each dist_old => nothing changes; reuse cache (skip scan).
// Margins (r*1.0001, aux*1.0002) dominate all f32 rounding => exact.
// Global selection = lexicographic max of (d, iv=0xFFFFFFFF-idx) over ALL points,
// partition-independent: per-thread scans tie-break by iv, wave DPP reduce,
// u64 partials in LDS, 1 barrier/iter (double-buffered). Bit-identical to dense.
template<int N, int NPOINT>
__global__ __launch_bounds__(512) void fps_kernel(const float* __restrict__ pos,
                                                  const unsigned* __restrict__ sordg,
                                                  int* __restrict__ out_idx,
                                                  float* __restrict__ out_pos,
                                                  float4* __restrict__ out_pp)
{
  constexpr int BLOCK = 512;
  constexpr int NPT = N / BLOCK;
  const int b = blockIdx.x;
  const float* P = pos + (size_t)b * N * 3;
  const unsigned* SORD = sordg + (size_t)b * N;
  int* oi = out_idx + (size_t)b * NPOINT;
  float* op = out_pos + (size_t)b * NPOINT * 3;
  float4* opp = out_pp + (size_t)b * NPOINT;

  __shared__ float4 spos[N];
  __shared__ u64 redk[2][8];

  const int t = threadIdx.x;
  const int lane = t & 63;
  const int wv = t >> 6;

  // stage all positions (by ORIGINAL index) for center broadcast + output emit
  for (int i = t; i < N; i += BLOCK) {
    float x = P[i*3+0], y = P[i*3+1], z = P[i*3+2];
    spos[i] = make_float4(x, y, z, (x*x + y*y) + z*z);
  }
  if (t == 0) oi[0] = 0;
  __syncthreads();

  // load this thread's Morton-block into registers
  float px[NPT], py[NPT], pz[NPT], dist[NPT];
  unsigned iv[NPT];
  float mnx = 3.4e38f, mxx = -3.4e38f, mny = 3.4e38f, mxy = -3.4e38f, mnz = 3.4e38f, mxz = -3.4e38f;
#pragma unroll
  for (int j = 0; j < NPT; ++j) {
    unsigned so = SORD[t * NPT + j];
    float4 v = spos[so];
    px[j] = v.x; py[j] = v.y; pz[j] = v.z; dist[j] = 1e10f;
    iv[j] = 0xFFFFFFFFu - so;
    mnx = fminf(mnx, v.x); mxx = fmaxf(mxx, v.x);
    mny = fminf(mny, v.y); mxy = fmaxf(mxy, v.y);
    mnz = fminf(mnz, v.z); mxz = fmaxf(mxz, v.z);
  }
  const float gcx = (mnx + mxx) * 0.5f, gcy = (mny + mxy) * 0.5f, gcz = (mnz + mxz) * 0.5f;
  float r2 = 0.f;
#pragma unroll
  for (int j = 0; j < NPT; ++j) {
    float dx = px[j] - gcx, dy = py[j] - gcy, dz = pz[j] - gcz;
    r2 = fmaxf(r2, fmaf(dz, dz, fmaf(dy, dy, dx * dx)));
  }
  const float r = sqrtf(r2) * 1.0001f;   // true upper bound on in-block radius
  float bd = 1e10f;
  unsigned biv = iv[0];
#pragma unroll
  for (int j = 1; j < NPT; ++j) biv = iv[j] > biv ? iv[j] : biv;  // lexmax of all-equal dists
  float sb = sqrtf(1e10f) + r;
  float aux = sb * sb * 1.0002f;

  int far = 0;
  for (int it = 1; it < NPOINT; ++it) {
    const float4 c = spos[far];              // LDS b128 broadcast
    if (t == ((it - 1) & (BLOCK - 1))) {     // emit sample it-1 (coords = current center)
      op[(it-1)*3+0] = c.x; op[(it-1)*3+1] = c.y; op[(it-1)*3+2] = c.z;
      opp[it-1] = c;
    }
    // prune test: can this center change ANY of my dists?
    const float dxg = c.x - gcx, dyg = c.y - gcy, dzg = c.z - gcz;
    const float ddg = fmaf(dzg, dzg, fmaf(dyg, dyg, dxg * dxg));
    if (ddg < aux) {
      bd = -1.f; biv = 0u;
#pragma unroll
      for (int j = 0; j < NPT; ++j) {
        float dx = px[j] - c.x, dy = py[j] - c.y, dz = pz[j] - c.z;
        float d  = fmaf(dz, dz, fmaf(dy, dy, dx * dx));   // EXACT same form as dense
        float nd = fminf(dist[j], d);
        dist[j] = nd;
        bool bt = (nd > bd) || ((nd == bd) && (iv[j] > biv));  // lexicographic (d, iv)
        bd  = bt ? nd : bd;
        biv = bt ? iv[j] : biv;
      }
      float s2 = sqrtf(bd) + r;
      aux = s2 * s2 * 1.0002f;
    }
    // wave lexmax: DPP max of d, then DPP max of tie-filtered iv
    const float wmax = wave64_max_f(bd);
    const unsigned cand = (bd == wmax) ? biv : 0u;
    const unsigned wiv = wave64_max_u(cand);
    const int par = it & 1;
    if (lane == 0) redk[par][wv] = ((u64)__float_as_uint(wmax) << 32) | (u64)wiv;
    __syncthreads();
    u64 key = ((u64)__float_as_uint(wmax) << 32) | (u64)wiv;
#pragma unroll
    for (int w2 = 0; w2 < 8; ++w2) {
      u64 o = redk[par][w2];
      if (o > key) key = o;
    }
    far = (int)(0xFFFFFFFFu - (unsigned)(key & 0xFFFFFFFFull));
    if (t == 0) oi[it] = far;
  }
  {
    const float4 c = spos[far];
    if (t == ((NPOINT - 1) & (BLOCK - 1))) {
      op[(NPOINT-1)*3+0] = c.x; op[(NPOINT-1)*3+1] = c.y; op[(NPOINT-1)*3+2] = c.z;
      opp[NPOINT-1] = c;
    }
  }
}

// ------------------------------------------------------------------
// Self-KNN (K=16), stable (d, idx) selection identical to lax.top_k(-d).
template<int G>
__global__ __launch_bounds__(256) void knn_kernel(const float4* __restrict__ pp, int M,
                                                  int* __restrict__ out)
{
  const int b = blockIdx.y;
  const float4* P = pp + (size_t)b * M;
  const int tid = threadIdx.x;
  constexpr int QPB = 256 / G;
  const int q = blockIdx.x * QPB + tid / G;
  const int seg = tid % G;

  __shared__ float4 tile[512];

  const float4 qp = P[q];
  const float qx = qp.x, qy = qp.y, qz = qp.z, qq = qp.w;

  float a[16]; int id[16];
#pragma unroll
  for (int j = 0; j < 16; ++j) { a[j] = 3.4e38f; id[j] = 0x7fffffff; }

  for (int t0 = 0; t0 < M; t0 += 512) {
    __syncthreads();
    tile[tid]       = P[t0 + tid];
    tile[tid + 256] = P[t0 + tid + 256];
    __syncthreads();
#pragma unroll 4
    for (int i = seg; i < 512; i += G) {
      float4 c = tile[i];
      float d = (qq + c.w) - 2.f * ((qx*c.x + qy*c.y) + qz*c.z);
      int gi = t0 + i;
      if (d < a[15]) {
        bool cc[16];
#pragma unroll
        for (int j = 0; j < 16; ++j) cc[j] = d < a[j];
#pragma unroll
        for (int j = 15; j >= 1; --j) {
          a[j]  = cc[j-1] ? a[j-1]  : (cc[j] ? d  : a[j]);
          id[j] = cc[j-1] ? id[j-1] : (cc[j] ? gi : id[j]);
        }
        if (cc[0]) { a[0] = d; id[0] = gi; }
      }
    }
  }
#pragma unroll
  for (int s = G/2; s >= 1; s >>= 1) {
    float bd[16]; int bi[16];
#pragma unroll
    for (int j = 0; j < 16; ++j) { bd[j] = __shfl_xor(a[j], s); bi[j] = __shfl_xor(id[j], s); }
#pragma unroll
    for (int j = 0; j < 16; ++j) {
      float od = bd[15-j]; int ob = bi[15-j];
      bool take = (od < a[j]) || (od == a[j] && ob < id[j]);
      a[j]  = take ? od : a[j];
      id[j] = take ? ob : id[j];
    }
#pragma unroll
    for (int st = 8; st >= 1; st >>= 1) {
#pragma unroll
      for (int j = 0; j < 16; ++j) {
        if ((j & st) == 0) {
          const int j2 = j + st;
          bool sw = (a[j2] < a[j]) || (a[j2] == a[j] && id[j2] < id[j]);
          float lod = sw ? a[j2] : a[j];  int loi = sw ? id[j2] : id[j];
          float hid = sw ? a[j]  : a[j2]; int hii = sw ? id[j]  : id[j2];
          a[j] = lod; id[j] = loi; a[j2] = hid; id[j2] = hii;
        }
      }
    }
  }
  if (seg == 0) {
    int* opp = out + ((size_t)b * M + q) * 16;
#pragma unroll
    for (int j = 0; j < 16; ++j) opp[j] = id[j];
  }
}

// ------------------------------------------------------------------
// three_nn + interpolation weights.
template<int G>
__global__ __launch_bounds__(256) void three_nn_kernel(const float4* __restrict__ qpp,
                                                       const float4* __restrict__ kpp,
                                                       int Mq, int Mk,
                                                       int* __restrict__ oidx, float* __restrict__ ow)
{
  const int b = blockIdx.y;
  const float4* Q  = qpp + (size_t)b * Mq;
  const float4* Kp = kpp + (size_t)b * Mk;
  const int tid = threadIdx.x;
  constexpr int QPB = 256 / G;
  const int q = blockIdx.x * QPB + tid / G;
  const int seg = tid % G;

  __shared__ float4 tile[512];

  const float4 qp = Q[q];
  const float qx = qp.x, qy = qp.y, qz = qp.z, qq = qp.w;

  float a[4]; int id[4];
#pragma unroll
  for (int j = 0; j < 4; ++j) { a[j] = 3.4e38f; id[j] = 0x7fffffff; }

  for (int t0 = 0; t0 < Mk; t0 += 512) {
    __syncthreads();
    tile[tid]       = Kp[t0 + tid];
    tile[tid + 256] = Kp[t0 + tid + 256];
    __syncthreads();
#pragma unroll 4
    for (int i = seg; i < 512; i += G) {
      float4 c = tile[i];
      float d = (qq + c.w) - 2.f * ((qx*c.x + qy*c.y) + qz*c.z);
      int gi = t0 + i;
      if (d < a[3]) {
        bool c0 = d < a[0], c1 = d < a[1], c2 = d < a[2];
        a[3]  = c2 ? a[2]  : d;                id[3] = c2 ? id[2] : gi;
        a[2]  = c1 ? a[1]  : (c2 ? d  : a[2]); id[2] = c1 ? id[1] : (c2 ? gi : id[2]);
        a[1]  = c0 ? a[0]  : (c1 ? d  : a[1]); id[1] = c0 ? id[0] : (c1 ? gi : id[1]);
        if (c0) { a[0] = d; id[0] = gi; }
      }
    }
  }
#pragma unroll
  for (int s = G/2; s >= 1; s >>= 1) {
    float bd[4]; int bi[4];
#pragma unroll
    for (int j = 0; j < 4; ++j) { bd[j] = __shfl_xor(a[j], s); bi[j] = __shfl_xor(id[j], s); }
#pragma unroll
    for (int j = 0; j < 4; ++j) {
      float od = bd[3-j]; int ob = bi[3-j];
      bool take = (od < a[j]) || (od == a[j] && ob < id[j]);
      a[j]  = take ? od : a[j];
      id[j] = take ? ob : id[j];
    }
#pragma unroll
    for (int st = 2; st >= 1; st >>= 1) {
#pragma unroll
      for (int j = 0; j < 4; ++j) {
        if ((j & st) == 0) {
          const int j2 = j + st;
          bool sw = (a[j2] < a[j]) || (a[j2] == a[j] && id[j2] < id[j]);
          float lod = sw ? a[j2] : a[j];  int loi = sw ? id[j2] : id[j];
          float hid = sw ? a[j]  : a[j2]; int hii = sw ? id[j]  : id[j2];
          a[j] = lod; id[j] = loi; a[j2] = hid; id[j2] = hii;
        }
      }
    }
  }
  if (seg == 0) {
    float d0 = fmaxf(a[0], 0.f), d1 = fmaxf(a[1], 0.f), d2 = fmaxf(a[2], 0.f);
    float r0 = 1.f/(d0 + 1e-8f), r1 = 1.f/(d1 + 1e-8f), r2 = 1.f/(d2 + 1e-8f);
    float s = (r0 + r1) + r2;
    size_t o = ((size_t)b * Mq + q) * 3;
    oidx[o+0] = id[0]; oidx[o+1] = id[1]; oidx[o+2] = id[2];
    ow[o+0] = r0/s; ow[o+1] = r1/s; ow[o+2] = r2/s;
  }
}

// ------------------------------------------------------------------
// Edge-conv neighbor mean: hbar[p] = [mean_k x[n_k], mean_k (pos_p - pos_nk), mean_k |rel|^2]
__global__ void hbar_kernel(const float* __restrict__ x, const float* __restrict__ pos,
                            const int* __restrict__ idx, int Mlvl, int C, int B,
                            float* __restrict__ out)
{
  const int Ct = C + 4;
  const int tot = B * Mlvl * Ct;
  int e = blockIdx.x * 256 + threadIdx.x;
  if (e >= tot) return;
  const int c  = e % Ct;
  const int p  = e / Ct;
  const int b  = p / Mlvl;
  const int lm = p % Mlvl;
  const int* ip = idx + (size_t)p * 16;
  float s = 0.f;
  if (c < C) {
    const float* xb = x + (size_t)b * Mlvl * C;
#pragma unroll 4
    for (int k = 0; k < 16; ++k) s += xb[(size_t)ip[k] * C + c];
  } else if (c < C + 3) {
    const int dd = c - C;
    const float* pb = pos + (size_t)b * Mlvl * 3;
    const float pc = pb[lm*3 + dd];
#pragma unroll 4
    for (int k = 0; k < 16; ++k) s += pc - pb[ip[k]*3 + dd];
  } else {
    const float* pb = pos + (size_t)b * Mlvl * 3;
    const float px = pb[lm*3+0], py = pb[lm*3+1], pz = pb[lm*3+2];
#pragma unroll 4
    for (int k = 0; k < 16; ++k) {
      int n = ip[k];
      float dx = px - pb[n*3+0], dy = py - pb[n*3+1], dz = pz - pb[n*3+2];
      s += (dx*dx + dy*dy) + dz*dz;
    }
  }
  out[e] = s * 0.0625f;
}

// ------------------------------------------------------------------
__global__ void interp_kernel(const float* __restrict__ f, const int* __restrict__ nidx,
                              const float* __restrict__ nw, int Mq, int Msub, int C, int B,
                              float* __restrict__ out)
{
  const int tot = B * Mq * C;
  int e = blockIdx.x * 256 + threadIdx.x;
  if (e >= tot) return;
  const int c = e % C;
  const int p = e / C;
  const int b = p / Mq;
  const float* fb = f + (size_t)b * Msub * C;
  const int* ip   = nidx + (size_t)p * 3;
  const float* wp = nw   + (size_t)p * 3;
  out[e] = (wp[0] * fb[(size_t)ip[0]*C + c] + wp[1] * fb[(size_t)ip[1]*C + c])
         +  wp[2] * fb[(size_t)ip[2]*C + c];
}

// ------------------------------------------------------------------
__global__ void gather_kernel(const float* __restrict__ src, const int* __restrict__ idx,
                              int Mq, int Msrc, int C, int B, float* __restrict__ dst)
{
  const int tot = B * Mq * C;
  int e = blockIdx.x * 256 + threadIdx.x;
  if (e >= tot) return;
  const int c = e % C;
  const int p = e / C;
  const int b = p / Mq;
  dst[e] = src[((size_t)b * Msrc + idx[p]) * C + c];
}

// ------------------------------------------------------------------
// Fused GEMM: out[M,F] = act( A[M,Ka]@W1[Ka,F] + B2[M,Kb]@W2[Kb,F] + bias )
__global__ __launch_bounds__(256) void gemm_kernel(const float* __restrict__ A, int Ka,
                                                   const float* __restrict__ B2, int Kb,
                                                   const float* __restrict__ W1,
                                                   const float* __restrict__ W2,
                                                   const float* __restrict__ bias,
                                                   float* __restrict__ out,
                                                   int M, int F, int act)
{
  __shared__ __align__(16) float As[16][64];
  __shared__ __align__(16) float Ws[16][64];
  const int tid  = threadIdx.x;
  const int row0 = blockIdx.x * 64;
  const int col0 = blockIdx.y * 64;
  const int tx = tid & 15, ty = tid >> 4;
  const int K = Ka + Kb;
  float acc[4][4] = {};
  for (int k0 = 0; k0 < K; k0 += 16) {
#pragma unroll
    for (int i = 0; i < 4; ++i) {
      int e = tid + i * 256;
      int m = e & 63, kk = e >> 6;
      int k = k0 + kk;
      float v = 0.f;
      if (k < Ka)     v = A [(size_t)(row0 + m) * Ka + k];
      else if (k < K) v = B2[(size_t)(row0 + m) * Kb + (k - Ka)];
      As[kk][m] = v;
      float wv = 0.f;
      if (k < Ka)     wv = W1[(size_t)k * F + col0 + m];
      else if (k < K) wv = W2[(size_t)(k - Ka) * F + col0 + m];
      Ws[kk][m] = wv;
    }
    __syncthreads();
#pragma unroll
    for (int kk = 0; kk < 16; ++kk) {
      const float4 a4 = *reinterpret_cast<const float4*>(&As[kk][ty * 4]);
      const float4 b4 = *reinterpret_cast<const float4*>(&Ws[kk][tx * 4]);
      const float av[4] = {a4.x, a4.y, a4.z, a4.w};
      const float bv[4] = {b4.x, b4.y, b4.z, b4.w};
#pragma unroll
      for (int i2 = 0; i2 < 4; ++i2)
#pragma unroll
        for (int j2 = 0; j2 < 4; ++j2)
          acc[i2][j2] = fmaf(av[i2], bv[j2], acc[i2][j2]);
    }
    __syncthreads();
  }
#pragma unroll
  for (int i2 = 0; i2 < 4; ++i2) {
    int r = row0 + ty * 4 + i2;
#pragma unroll
    for (int j2 = 0; j2 < 4; ++j2) {
      int cc = col0 + tx * 4 + j2;
      float v = acc[i2][j2];
      if (bias) v += bias[cc];
      if (act)  v = leakyf(v);
      out[(size_t)r * F + cc] = v;
    }
  }
}

// ------------------------------------------------------------------
extern "C" void kernel_launch(void* const* d_in, const int* in_sizes, int n_in,
                              void* d_out, int out_size, void* d_ws, size_t ws_size,
                              hipStream_t stream)
{
  (void)in_sizes; (void)n_in; (void)out_size; (void)ws_size;
  const float* x          = (const float*)d_in[0];   // [2,8192,4]
  const float* pos        = (const float*)d_in[1];   // [2,8192,3]
  const float* w_self0    = (const float*)d_in[2];   // [4,64]
  const float* w_edge0    = (const float*)d_in[3];   // [8,64]
  const float* w_self1    = (const float*)d_in[4];   // [64,128]
  const float* w_edge1    = (const float*)d_in[5];   // [68,128]
  const float* w_self2    = (const float*)d_in[6];   // [128,256]
  const float* w_edge2    = (const float*)d_in[7];   // [132,256]
  const float* w_up1      = (const float*)d_in[8];   // [384,128]
  const float* b_up1      = (const float*)d_in[9];   // [128]
  const float* w_upc1s    = (const float*)d_in[10];  // [128,128]
  const float* w_upc1e    = (const float*)d_in[11];  // [132,128]
  const float* w_up0      = (const float*)d_in[12];  // [192,64]
  const float* b_up0      = (const float*)d_in[13];  // [64]
  const float* w_upc0s    = (const float*)d_in[14];  // [64,64]
  const float* w_upc0e    = (const float*)d_in[15];  // [68,64]
  const float* w_out      = (const float*)d_in[16];  // [64,128]
  const float* b_out      = (const float*)d_in[17];  // [128]
  float* out = (float*)d_out;                        // [2,8192,128]

  char* ws = (char*)d_ws;
  size_t off = 0;
  auto alloc = [&](size_t nbytes) -> void* {
    off = (off + 255) & ~(size_t)255;
    void* p = ws + off;
    off += nbytes;
    return p;
  };
  int*    knn0   = (int*)   alloc((size_t)2*8192*16*4);
  int*    knn1   = (int*)   alloc((size_t)2*4096*16*4);
  int*    knn2   = (int*)   alloc((size_t)2*2048*16*4);
  int*    idx1   = (int*)   alloc((size_t)2*4096*4);
  int*    idx2   = (int*)   alloc((size_t)2*2048*4);
  float*  pos1   = (float*) alloc((size_t)2*4096*3*4);
  float*  pos2   = (float*) alloc((size_t)2*2048*3*4);
  float4* pp0    = (float4*)alloc((size_t)2*8192*16);
  float4* pp1    = (float4*)alloc((size_t)2*4096*16);
  float4* pp2    = (float4*)alloc((size_t)2*2048*16);
  float*  feat0  = (float*) alloc((size_t)2*8192*64*4);
  float*  feat0g = (float*) alloc((size_t)2*4096*64*4);
  float*  feat1  = (float*) alloc((size_t)2*4096*128*4);
  float*  feat1g = (float*) alloc((size_t)2*2048*128*4);
  float*  feat2  = (float*) alloc((size_t)2*2048*256*4);
  int*    nn1i   = (int*)   alloc((size_t)2*4096*3*4);
  float*  nn1w   = (float*) alloc((size_t)2*4096*3*4);
  int*    nn0i   = (int*)   alloc((size_t)2*8192*3*4);
  float*  nn0w   = (float*) alloc((size_t)2*8192*3*4);
  float*  interp = (float*) alloc((size_t)2*4096*256*4);  // reused for interp0 (same size)
  float*  hbar   = (float*) alloc((size_t)2*8192*68*4);   // max of all hbar stages
  float*  fupa   = (float*) alloc((size_t)2*4096*128*4);  // fup1a, later fup0a (same size)
  float*  fup1   = (float*) alloc((size_t)2*4096*128*4);
  float*  fout   = (float*) alloc((size_t)2*8192*64*4);
  unsigned* sord1 = (unsigned*)alloc((size_t)2*8192*4);
  unsigned* sord2 = (unsigned*)alloc((size_t)2*4096*4);

  // --- packed pos level 0 + Morton prep for FPS level 1 ---
  pack_kernel<<<64, 256, 0, stream>>>(pos, 2*8192, pp0);
  fps_prep_kernel<8192><<<2, 512, 0, stream>>>(pos, sord1);
  // --- level 0: knn + edge conv ---
  knn_kernel<16><<<dim3(512, 2), 256, 0, stream>>>(pp0, 8192, knn0);
  hbar_kernel<<<512, 256, 0, stream>>>(x, pos, knn0, 8192, 4, 2, hbar);
  gemm_kernel<<<dim3(256, 1), 256, 0, stream>>>(x, 4, hbar, 8, w_self0, w_edge0, nullptr,
                                                feat0, 16384, 64, 1);
  // --- FPS level 1 + downsample ---
  fps_kernel<8192, 4096><<<2, 512, 0, stream>>>(pos, sord1, idx1, pos1, pp1);
  fps_prep_kernel<4096><<<2, 512, 0, stream>>>(pos1, sord2);
  gather_kernel<<<2048, 256, 0, stream>>>(feat0, idx1, 4096, 8192, 64, 2, feat0g);
  knn_kernel<16><<<dim3(256, 2), 256, 0, stream>>>(pp1, 4096, knn1);
  hbar_kernel<<<2176, 256, 0, stream>>>(feat0g, pos1, knn1, 4096, 64, 2, hbar);
  gemm_kernel<<<dim3(128, 2), 256, 0, stream>>>(feat0g, 64, hbar, 68, w_self1, w_edge1, nullptr,
                                                feat1, 8192, 128, 1);
  // --- FPS level 2 + downsample ---
  fps_kernel<4096, 2048><<<2, 512, 0, stream>>>(pos1, sord2, idx2, pos2, pp2);
  gather_kernel<<<2048, 256, 0, stream>>>(feat1, idx2, 2048, 4096, 128, 2, feat1g);
  knn_kernel<16><<<dim3(128, 2), 256, 0, stream>>>(pp2, 2048, knn2);
  hbar_kernel<<<2112, 256, 0, stream>>>(feat1g, pos2, knn2, 2048, 128, 2, hbar);
  gemm_kernel<<<dim3(64, 4), 256, 0, stream>>>(feat1g, 128, hbar, 132, w_self2, w_edge2, nullptr,
                                               feat2, 4096, 256, 1);
  // --- up level 1 ---
  three_nn_kernel<16><<<dim3(256, 2), 256, 0, stream>>>(pp1, pp2, 4096, 2048, nn1i, nn1w);
  interp_kernel<<<8192, 256, 0, stream>>>(feat2, nn1i, nn1w, 4096, 2048, 256, 2, interp);
  gemm_kernel<<<dim3(128, 2), 256, 0, stream>>>(interp, 256, feat1, 128,
                                                w_up1, w_up1 + (size_t)256 * 128, b_up1,
                                                fupa, 8192, 128, 1);
  hbar_kernel<<<4224, 256, 0, stream>>>(fupa, pos1, knn1, 4096, 128, 2, hbar);
  gemm_kernel<<<dim3(128, 2), 256, 0, stream>>>(fupa, 128, hbar, 132, w_upc1s, w_upc1e, nullptr,
                                                fup1, 8192, 128, 1);
  // --- up level 0 ---
  three_nn_kernel<16><<<dim3(512, 2), 256, 0, stream>>>(pp0, pp1, 8192, 4096, nn0i, nn0w);
  interp_kernel<<<8192, 256, 0, stream>>>(fup1, nn0i, nn0w, 8192, 4096, 128, 2, interp);
  gemm_kernel<<<dim3(256, 1), 256, 0, stream>>>(interp, 128, feat0, 64,
                                                w_up0, w_up0 + (size_t)128 * 64, b_up0,
                                                fupa, 16384, 64, 1);
  hbar_kernel<<<4352, 256, 0, stream>>>(fupa, pos, knn0, 8192, 64, 2, hbar);
  gemm_kernel<<<dim3(256, 1), 256, 0, stream>>>(fupa, 64, hbar, 68, w_upc0s, w_upc0e, nullptr,
                                                fout, 16384, 64, 1);
  // --- final projection ---
  gemm_kernel<<<dim3(256, 2), 256, 0, stream>>>(fout, 64, nullptr, 0, w_out, nullptr, b_out,
                                                out, 16384, 128, 0);
}

// Round 7
// 5958.430 us; speedup vs baseline: 1.8669x; 1.8669x over previous
//
#include <hip/hip_runtime.h>
#include <cstdint>

typedef unsigned long long u64;

static __device__ __forceinline__ float leakyf(float v) { return v >= 0.f ? v : 0.2f * v; }

// ------------------------------------------------------------------
// Pack [M,3] positions into float4(x,y,z,|p|^2). ss association (x*x+y*y)+z*z
// must match the query-side qq usage in knn/three_nn.
__global__ void pack_kernel(const float* __restrict__ pos, int total, float4* __restrict__ out)
{
  int i = blockIdx.x * 256 + threadIdx.x;
  if (i >= total) return;
  float x = pos[i*3+0], y = pos[i*3+1], z = pos[i*3+2];
  out[i] = make_float4(x, y, z, (x*x + y*y) + z*z);
}

// ------------------------------------------------------------------
// DPP wave64 u64-max reduction (rocPRIM pattern: row_shr 1/2/4/8 + row_bcast15/31;
// lane 63 accumulates the total; readlane(63) broadcasts). bound_ctrl=false with
// old=x => lanes without a source keep x; max(x,x)=x is identity — exact.
// Validated bit-exact on this problem by R5 (two-chain variant, same pattern).
template<int CTRL>
static __device__ __forceinline__ u64 dpp_max_u64_step(u64 x)
{
  unsigned lo = (unsigned)x, hi = (unsigned)(x >> 32);
  unsigned ylo = (unsigned)__builtin_amdgcn_update_dpp((int)lo, (int)lo, CTRL, 0xF, 0xF, false);
  unsigned yhi = (unsigned)__builtin_amdgcn_update_dpp((int)hi, (int)hi, CTRL, 0xF, 0xF, false);
  u64 y = ((u64)yhi << 32) | (u64)ylo;
  return x > y ? x : y;
}
static __device__ __forceinline__ u64 wave64_max_u64(u64 x)
{
  x = dpp_max_u64_step<0x111>(x);  // row_shr:1
  x = dpp_max_u64_step<0x112>(x);  // row_shr:2
  x = dpp_max_u64_step<0x114>(x);  // row_shr:4
  x = dpp_max_u64_step<0x118>(x);  // row_shr:8
  x = dpp_max_u64_step<0x142>(x);  // row_bcast:15
  x = dpp_max_u64_step<0x143>(x);  // row_bcast:31
  unsigned lo = (unsigned)__builtin_amdgcn_readlane((int)(unsigned)x, 63);
  unsigned hi = (unsigned)__builtin_amdgcn_readlane((int)(unsigned)(x >> 32), 63);
  return ((u64)hi << 32) | (u64)lo;
}

// ------------------------------------------------------------------
// Furthest point sampling (exact, matches jax scan semantics):
// out[0]=0; for it in 1..NP-1: dists=min(dists, d(.,pos[out[it-1]])); out[it]=argmax (first max).
// One block (256 threads = 4 waves, 1 wave/SIMD) per batch, dense register update.
// Per iter: LDS b128 broadcast of center; per-thread scan (strict > keeps lowest idx);
// u64 key (f32 bits of d || 0xFFFFFFFF-idx) -> single 6-step DPP u64 max per wave;
// 4 partials in LDS (double-buffered), 1 barrier, all threads combine via 2x b128.
// Selection sequence bit-identical to R5 (associative exact max, topology change only).
template<int N, int NPOINT>
__global__ __launch_bounds__(256) void fps_kernel(const float* __restrict__ pos,
                                                  int* __restrict__ out_idx,
                                                  float* __restrict__ out_pos,
                                                  float4* __restrict__ out_pp)
{
  constexpr int BLOCK = 256;
  constexpr int NPT = N / BLOCK;
  const int b = blockIdx.x;
  const float* P = pos + (size_t)b * N * 3;
  int* oi = out_idx + (size_t)b * NPOINT;
  float* op = out_pos + (size_t)b * NPOINT * 3;
  float4* opp = out_pp + (size_t)b * NPOINT;

  __shared__ float4 spos[N];
  __shared__ __align__(16) u64 redk[2][4];

  const int t = threadIdx.x;
  const int lane = t & 63;
  const int wv = t >> 6;

  float px[NPT], py[NPT], pz[NPT], dist[NPT];
  unsigned iv[NPT];  // 0xFFFFFFFF - global_idx (tie-break payload)
#pragma unroll
  for (int j = 0; j < NPT; ++j) {
    int i = t + j * BLOCK;
    float x = P[i*3+0], y = P[i*3+1], z = P[i*3+2];
    spos[i] = make_float4(x, y, z, (x*x + y*y) + z*z);
    px[j] = x; py[j] = y; pz[j] = z; dist[j] = 1e10f;
    iv[j] = 0xFFFFFFFFu - (unsigned)i;
  }
  if (t == 0) oi[0] = 0;
  __syncthreads();

  int far = 0;
  for (int it = 1; it < NPOINT; ++it) {
    const float4 c = spos[far];              // one b128 broadcast read
    if (t == ((it - 1) & (BLOCK - 1))) {     // emit sample it-1 (coords = current center)
      op[(it-1)*3+0] = c.x; op[(it-1)*3+1] = c.y; op[(it-1)*3+2] = c.z;
      opp[it-1] = c;
    }
    float bd = -1.f; unsigned biv = 0u;
#pragma unroll
    for (int j = 0; j < NPT; ++j) {
      float dx = px[j] - c.x, dy = py[j] - c.y, dz = pz[j] - c.z;
      float d  = fmaf(dz, dz, fmaf(dy, dy, dx * dx));
      float nd = fminf(dist[j], d);
      dist[j] = nd;
      bool bt = nd > bd;                     // strict >: ties keep earlier j = lower idx
      bd  = bt ? nd : bd;
      biv = bt ? iv[j] : biv;
    }
    // wave lexmax via single u64 DPP chain (bd >= 0 => f32 bits monotone as u32)
    u64 key = ((u64)__float_as_uint(bd) << 32) | (u64)biv;
    key = wave64_max_u64(key);
    const int par = it & 1;
    if (lane == 0) redk[par][wv] = key;
    __syncthreads();
    // all threads combine the 4 wave partials (vectorized b128 reads, uniform addr)
    const ulonglong2 p01 = *reinterpret_cast<const ulonglong2*>(&redk[par][0]);
    const ulonglong2 p23 = *reinterpret_cast<const ulonglong2*>(&redk[par][2]);
    u64 k0 = p01.x > p01.y ? p01.x : p01.y;
    u64 k1 = p23.x > p23.y ? p23.x : p23.y;
    key = k0 > k1 ? k0 : k1;
    far = (int)(0xFFFFFFFFu - (unsigned)(key & 0xFFFFFFFFull));
    if (t == 0) oi[it] = far;
  }
  // flush the last sample
  {
    const float4 c = spos[far];
    if (t == ((NPOINT - 1) & (BLOCK - 1))) {
      op[(NPOINT-1)*3+0] = c.x; op[(NPOINT-1)*3+1] = c.y; op[(NPOINT-1)*3+2] = c.z;
      opp[NPOINT-1] = c;
    }
  }
}

// ------------------------------------------------------------------
// Self-KNN (K=16), stable (d, idx) selection identical to lax.top_k(-d).
// G=16 segments per query; per-seg sorted top-16 in registers; segments merged
// in-wave via shfl_xor bitonic rounds with lexicographic (d, idx) comparator.
template<int G>
__global__ __launch_bounds__(256) void knn_kernel(const float4* __restrict__ pp, int M,
                                                  int* __restrict__ out)
{
  const int b = blockIdx.y;
  const float4* P = pp + (size_t)b * M;
  const int tid = threadIdx.x;
  constexpr int QPB = 256 / G;
  const int q = blockIdx.x * QPB + tid / G;
  const int seg = tid % G;

  __shared__ float4 tile[512];

  const float4 qp = P[q];
  const float qx = qp.x, qy = qp.y, qz = qp.z, qq = qp.w;

  float a[16]; int id[16];
#pragma unroll
  for (int j = 0; j < 16; ++j) { a[j] = 3.4e38f; id[j] = 0x7fffffff; }

  for (int t0 = 0; t0 < M; t0 += 512) {
    __syncthreads();
    tile[tid]       = P[t0 + tid];
    tile[tid + 256] = P[t0 + tid + 256];
    __syncthreads();
#pragma unroll 4
    for (int i = seg; i < 512; i += G) {
      float4 c = tile[i];
      float d = (qq + c.w) - 2.f * ((qx*c.x + qy*c.y) + qz*c.z);
      int gi = t0 + i;
      if (d < a[15]) {               // insertion, stable: ties keep earlier idx
        bool cc[16];
#pragma unroll
        for (int j = 0; j < 16; ++j) cc[j] = d < a[j];
#pragma unroll
        for (int j = 15; j >= 1; --j) {
          a[j]  = cc[j-1] ? a[j-1]  : (cc[j] ? d  : a[j]);
          id[j] = cc[j-1] ? id[j-1] : (cc[j] ? gi : id[j]);
        }
        if (cc[0]) { a[0] = d; id[0] = gi; }
      }
    }
  }
  // butterfly merge across G segments
#pragma unroll
  for (int s = G/2; s >= 1; s >>= 1) {
    float bd[16]; int bi[16];
#pragma unroll
    for (int j = 0; j < 16; ++j) { bd[j] = __shfl_xor(a[j], s); bi[j] = __shfl_xor(id[j], s); }
#pragma unroll
    for (int j = 0; j < 16; ++j) {       // lower half of bitonic 32-seq [a asc | b desc]
      float od = bd[15-j]; int ob = bi[15-j];
      bool take = (od < a[j]) || (od == a[j] && ob < id[j]);
      a[j]  = take ? od : a[j];
      id[j] = take ? ob : id[j];
    }
#pragma unroll
    for (int st = 8; st >= 1; st >>= 1) { // bitonic merge
#pragma unroll
      for (int j = 0; j < 16; ++j) {
        if ((j & st) == 0) {
          const int j2 = j + st;
          bool sw = (a[j2] < a[j]) || (a[j2] == a[j] && id[j2] < id[j]);
          float lod = sw ? a[j2] : a[j];  int loi = sw ? id[j2] : id[j];
          float hid = sw ? a[j]  : a[j2]; int hii = sw ? id[j]  : id[j2];
          a[j] = lod; id[j] = loi; a[j2] = hid; id[j2] = hii;
        }
      }
    }
  }
  if (seg == 0) {
    int* opp = out + ((size_t)b * M + q) * 16;
#pragma unroll
    for (int j = 0; j < 16; ++j) opp[j] = id[j];
  }
}

// ------------------------------------------------------------------
// three_nn + interpolation weights. Same G-segmented structure with register
// top-4 lists (4th slot only to make the bitonic trick power-of-two).
template<int G>
__global__ __launch_bounds__(256) void three_nn_kernel(const float4* __restrict__ qpp,
                                                       const float4* __restrict__ kpp,
                                                       int Mq, int Mk,
                                                       int* __restrict__ oidx, float* __restrict__ ow)
{
  const int b = blockIdx.y;
  const float4* Q  = qpp + (size_t)b * Mq;
  const float4* Kp = kpp + (size_t)b * Mk;
  const int tid = threadIdx.x;
  constexpr int QPB = 256 / G;
  const int q = blockIdx.x * QPB + tid / G;
  const int seg = tid % G;

  __shared__ float4 tile[512];

  const float4 qp = Q[q];
  const float qx = qp.x, qy = qp.y, qz = qp.z, qq = qp.w;

  float a[4]; int id[4];
#pragma unroll
  for (int j = 0; j < 4; ++j) { a[j] = 3.4e38f; id[j] = 0x7fffffff; }

  for (int t0 = 0; t0 < Mk; t0 += 512) {
    __syncthreads();
    tile[tid]       = Kp[t0 + tid];
    tile[tid + 256] = Kp[t0 + tid + 256];
    __syncthreads();
#pragma unroll 4
    for (int i = seg; i < 512; i += G) {
      float4 c = tile[i];
      float d = (qq + c.w) - 2.f * ((qx*c.x + qy*c.y) + qz*c.z);
      int gi = t0 + i;
      if (d < a[3]) {
        bool c0 = d < a[0], c1 = d < a[1], c2 = d < a[2];
        a[3]  = c2 ? a[2]  : d;                id[3] = c2 ? id[2] : gi;
        a[2]  = c1 ? a[1]  : (c2 ? d  : a[2]); id[2] = c1 ? id[1] : (c2 ? gi : id[2]);
        a[1]  = c0 ? a[0]  : (c1 ? d  : a[1]); id[1] = c0 ? id[0] : (c1 ? gi : id[1]);
        if (c0) { a[0] = d; id[0] = gi; }
      }
    }
  }
#pragma unroll
  for (int s = G/2; s >= 1; s >>= 1) {
    float bd[4]; int bi[4];
#pragma unroll
    for (int j = 0; j < 4; ++j) { bd[j] = __shfl_xor(a[j], s); bi[j] = __shfl_xor(id[j], s); }
#pragma unroll
    for (int j = 0; j < 4; ++j) {
      float od = bd[3-j]; int ob = bi[3-j];
      bool take = (od < a[j]) || (od == a[j] && ob < id[j]);
      a[j]  = take ? od : a[j];
      id[j] = take ? ob : id[j];
    }
#pragma unroll
    for (int st = 2; st >= 1; st >>= 1) {
#pragma unroll
      for (int j = 0; j < 4; ++j) {
        if ((j & st) == 0) {
          const int j2 = j + st;
          bool sw = (a[j2] < a[j]) || (a[j2] == a[j] && id[j2] < id[j]);
          float lod = sw ? a[j2] : a[j];  int loi = sw ? id[j2] : id[j];
          float hid = sw ? a[j]  : a[j2]; int hii = sw ? id[j]  : id[j2];
          a[j] = lod; id[j] = loi; a[j2] = hid; id[j2] = hii;
        }
      }
    }
  }
  if (seg == 0) {
    float d0 = fmaxf(a[0], 0.f), d1 = fmaxf(a[1], 0.f), d2 = fmaxf(a[2], 0.f);
    float r0 = 1.f/(d0 + 1e-8f), r1 = 1.f/(d1 + 1e-8f), r2 = 1.f/(d2 + 1e-8f);
    float s = (r0 + r1) + r2;
    size_t o = ((size_t)b * Mq + q) * 3;
    oidx[o+0] = id[0]; oidx[o+1] = id[1]; oidx[o+2] = id[2];
    ow[o+0] = r0/s; ow[o+1] = r1/s; ow[o+2] = r2/s;
  }
}

// ------------------------------------------------------------------
// Edge-conv neighbor mean: hbar[p] = [mean_k x[n_k], mean_k (pos_p - pos_nk), mean_k |rel|^2]
__global__ void hbar_kernel(const float* __restrict__ x, const float* __restrict__ pos,
                            const int* __restrict__ idx, int Mlvl, int C, int B,
                            float* __restrict__ out)
{
  const int Ct = C + 4;
  const int tot = B * Mlvl * Ct;
  int e = blockIdx.x * 256 + threadIdx.x;
  if (e >= tot) return;
  const int c  = e % Ct;
  const int p  = e / Ct;
  const int b  = p / Mlvl;
  const int lm = p % Mlvl;
  const int* ip = idx + (size_t)p * 16;
  float s = 0.f;
  if (c < C) {
    const float* xb = x + (size_t)b * Mlvl * C;
#pragma unroll 4
    for (int k = 0; k < 16; ++k) s += xb[(size_t)ip[k] * C + c];
  } else if (c < C + 3) {
    const int dd = c - C;
    const float* pb = pos + (size_t)b * Mlvl * 3;
    const float pc = pb[lm*3 + dd];
#pragma unroll 4
    for (int k = 0; k < 16; ++k) s += pc - pb[ip[k]*3 + dd];
  } else {
    const float* pb = pos + (size_t)b * Mlvl * 3;
    const float px = pb[lm*3+0], py = pb[lm*3+1], pz = pb[lm*3+2];
#pragma unroll 4
    for (int k = 0; k < 16; ++k) {
      int n = ip[k];
      float dx = px - pb[n*3+0], dy = py - pb[n*3+1], dz = pz - pb[n*3+2];
      s += (dx*dx + dy*dy) + dz*dz;
    }
  }
  out[e] = s * 0.0625f;
}

// ------------------------------------------------------------------
__global__ void interp_kernel(const float* __restrict__ f, const int* __restrict__ nidx,
                              const float* __restrict__ nw, int Mq, int Msub, int C, int B,
                              float* __restrict__ out)
{
  const int tot = B * Mq * C;
  int e = blockIdx.x * 256 + threadIdx.x;
  if (e >= tot) return;
  const int c = e % C;
  const int p = e / C;
  const int b = p / Mq;
  const float* fb = f + (size_t)b * Msub * C;
  const int* ip   = nidx + (size_t)p * 3;
  const float* wp = nw   + (size_t)p * 3;
  out[e] = (wp[0] * fb[(size_t)ip[0]*C + c] + wp[1] * fb[(size_t)ip[1]*C + c])
         +  wp[2] * fb[(size_t)ip[2]*C + c];
}

// ------------------------------------------------------------------
__global__ void gather_kernel(const float* __restrict__ src, const int* __restrict__ idx,
                              int Mq, int Msrc, int C, int B, float* __restrict__ dst)
{
  const int tot = B * Mq * C;
  int e = blockIdx.x * 256 + threadIdx.x;
  if (e >= tot) return;
  const int c = e % C;
  const int p = e / C;
  const int b = p / Mq;
  dst[e] = src[((size_t)b * Msrc + idx[p]) * C + c];
}

// ------------------------------------------------------------------
// Fused GEMM: out[M,F] = act( A[M,Ka]@W1[Ka,F] + B2[M,Kb]@W2[Kb,F] + bias )
// 64x64 tile, BK=16, 256 threads, 4x4 micro-tile. M,F multiples of 64; K zero-padded.
__global__ __launch_bounds__(256) void gemm_kernel(const float* __restrict__ A, int Ka,
                                                   const float* __restrict__ B2, int Kb,
                                                   const float* __restrict__ W1,
                                                   const float* __restrict__ W2,
                                                   const float* __restrict__ bias,
                                                   float* __restrict__ out,
                                                   int M, int F, int act)
{
  __shared__ __align__(16) float As[16][64];
  __shared__ __align__(16) float Ws[16][64];
  const int tid  = threadIdx.x;
  const int row0 = blockIdx.x * 64;
  const int col0 = blockIdx.y * 64;
  const int tx = tid & 15, ty = tid >> 4;
  const int K = Ka + Kb;
  float acc[4][4] = {};
  for (int k0 = 0; k0 < K; k0 += 16) {
#pragma unroll
    for (int i = 0; i < 4; ++i) {
      int e = tid + i * 256;
      int m = e & 63, kk = e >> 6;
      int k = k0 + kk;
      float v = 0.f;
      if (k < Ka)     v = A [(size_t)(row0 + m) * Ka + k];
      else if (k < K) v = B2[(size_t)(row0 + m) * Kb + (k - Ka)];
      As[kk][m] = v;
      float wv = 0.f;
      if (k < Ka)     wv = W1[(size_t)k * F + col0 + m];
      else if (k < K) wv = W2[(size_t)(k - Ka) * F + col0 + m];
      Ws[kk][m] = wv;
    }
    __syncthreads();
#pragma unroll
    for (int kk = 0; kk < 16; ++kk) {
      const float4 a4 = *reinterpret_cast<const float4*>(&As[kk][ty * 4]);
      const float4 b4 = *reinterpret_cast<const float4*>(&Ws[kk][tx * 4]);
      const float av[4] = {a4.x, a4.y, a4.z, a4.w};
      const float bv[4] = {b4.x, b4.y, b4.z, b4.w};
#pragma unroll
      for (int i2 = 0; i2 < 4; ++i2)
#pragma unroll
        for (int j2 = 0; j2 < 4; ++j2)
          acc[i2][j2] = fmaf(av[i2], bv[j2], acc[i2][j2]);
    }
    __syncthreads();
  }
#pragma unroll
  for (int i2 = 0; i2 < 4; ++i2) {
    int r = row0 + ty * 4 + i2;
#pragma unroll
    for (int j2 = 0; j2 < 4; ++j2) {
      int cc = col0 + tx * 4 + j2;
      float v = acc[i2][j2];
      if (bias) v += bias[cc];
      if (act)  v = leakyf(v);
      out[(size_t)r * F + cc] = v;
    }
  }
}

// ------------------------------------------------------------------
extern "C" void kernel_launch(void* const* d_in, const int* in_sizes, int n_in,
                              void* d_out, int out_size, void* d_ws, size_t ws_size,
                              hipStream_t stream)
{
  (void)in_sizes; (void)n_in; (void)out_size; (void)ws_size;
  const float* x          = (const float*)d_in[0];   // [2,8192,4]
  const float* pos        = (const float*)d_in[1];   // [2,8192,3]
  const float* w_self0    = (const float*)d_in[2];   // [4,64]
  const float* w_edge0    = (const float*)d_in[3];   // [8,64]
  const float* w_self1    = (const float*)d_in[4];   // [64,128]
  const float* w_edge1    = (const float*)d_in[5];   // [68,128]
  const float* w_self2    = (const float*)d_in[6];   // [128,256]
  const float* w_edge2    = (const float*)d_in[7];   // [132,256]
  const float* w_up1      = (const float*)d_in[8];   // [384,128]
  const float* b_up1      = (const float*)d_in[9];   // [128]
  const float* w_upc1s    = (const float*)d_in[10];  // [128,128]
  const float* w_upc1e    = (const float*)d_in[11];  // [132,128]
  const float* w_up0      = (const float*)d_in[12];  // [192,64]
  const float* b_up0      = (const float*)d_in[13];  // [64]
  const float* w_upc0s    = (const float*)d_in[14];  // [64,64]
  const float* w_upc0e    = (const float*)d_in[15];  // [68,64]
  const float* w_out      = (const float*)d_in[16];  // [64,128]
  const float* b_out      = (const float*)d_in[17];  // [128]
  float* out = (float*)d_out;                        // [2,8192,128]

  char* ws = (char*)d_ws;
  size_t off = 0;
  auto alloc = [&](size_t nbytes) -> void* {
    off = (off + 255) & ~(size_t)255;
    void* p = ws + off;
    off += nbytes;
    return p;
  };
  int*    knn0   = (int*)   alloc((size_t)2*8192*16*4);
  int*    knn1   = (int*)   alloc((size_t)2*4096*16*4);
  int*    knn2   = (int*)   alloc((size_t)2*2048*16*4);
  int*    idx1   = (int*)   alloc((size_t)2*4096*4);
  int*    idx2   = (int*)   alloc((size_t)2*2048*4);
  float*  pos1   = (float*) alloc((size_t)2*4096*3*4);
  float*  pos2   = (float*) alloc((size_t)2*2048*3*4);
  float4* pp0    = (float4*)alloc((size_t)2*8192*16);
  float4* pp1    = (float4*)alloc((size_t)2*4096*16);
  float4* pp2    = (float4*)alloc((size_t)2*2048*16);
  float*  feat0  = (float*) alloc((size_t)2*8192*64*4);
  float*  feat0g = (float*) alloc((size_t)2*4096*64*4);
  float*  feat1  = (float*) alloc((size_t)2*4096*128*4);
  float*  feat1g = (float*) alloc((size_t)2*2048*128*4);
  float*  feat2  = (float*) alloc((size_t)2*2048*256*4);
  int*    nn1i   = (int*)   alloc((size_t)2*4096*3*4);
  float*  nn1w   = (float*) alloc((size_t)2*4096*3*4);
  int*    nn0i   = (int*)   alloc((size_t)2*8192*3*4);
  float*  nn0w   = (float*) alloc((size_t)2*8192*3*4);
  float*  interp = (float*) alloc((size_t)2*4096*256*4);  // reused for interp0 (same size)
  float*  hbar   = (float*) alloc((size_t)2*8192*68*4);   // max of all hbar stages
  float*  fupa   = (float*) alloc((size_t)2*4096*128*4);  // fup1a, later fup0a (same size)
  float*  fup1   = (float*) alloc((size_t)2*4096*128*4);
  float*  fout   = (float*) alloc((size_t)2*8192*64*4);

  // --- packed pos level 0 ---
  pack_kernel<<<64, 256, 0, stream>>>(pos, 2*8192, pp0);
  // --- level 0: knn + edge conv ---
  knn_kernel<16><<<dim3(512, 2), 256, 0, stream>>>(pp0, 8192, knn0);
  hbar_kernel<<<512, 256, 0, stream>>>(x, pos, knn0, 8192, 4, 2, hbar);
  gemm_kernel<<<dim3(256, 1), 256, 0, stream>>>(x, 4, hbar, 8, w_self0, w_edge0, nullptr,
                                                feat0, 16384, 64, 1);
  // --- FPS level 1 + downsample ---
  fps_kernel<8192, 4096><<<2, 256, 0, stream>>>(pos, idx1, pos1, pp1);
  gather_kernel<<<2048, 256, 0, stream>>>(feat0, idx1, 4096, 8192, 64, 2, feat0g);
  knn_kernel<16><<<dim3(256, 2), 256, 0, stream>>>(pp1, 4096, knn1);
  hbar_kernel<<<2176, 256, 0, stream>>>(feat0g, pos1, knn1, 4096, 64, 2, hbar);
  gemm_kernel<<<dim3(128, 2), 256, 0, stream>>>(feat0g, 64, hbar, 68, w_self1, w_edge1, nullptr,
                                                feat1, 8192, 128, 1);
  // --- FPS level 2 + downsample ---
  fps_kernel<4096, 2048><<<2, 256, 0, stream>>>(pos1, idx2, pos2, pp2);
  gather_kernel<<<2048, 256, 0, stream>>>(feat1, idx2, 2048, 4096, 128, 2, feat1g);
  knn_kernel<16><<<dim3(128, 2), 256, 0, stream>>>(pp2, 2048, knn2);
  hbar_kernel<<<2112, 256, 0, stream>>>(feat1g, pos2, knn2, 2048, 128, 2, hbar);
  gemm_kernel<<<dim3(64, 4), 256, 0, stream>>>(feat1g, 128, hbar, 132, w_self2, w_edge2, nullptr,
                                               feat2, 4096, 256, 1);
  // --- up level 1: interp(feat2)->pos1, concat feat1, linear, edge conv ---
  three_nn_kernel<16><<<dim3(256, 2), 256, 0, stream>>>(pp1, pp2, 4096, 2048, nn1i, nn1w);
  interp_kernel<<<8192, 256, 0, stream>>>(feat2, nn1i, nn1w, 4096, 2048, 256, 2, interp);
  gemm_kernel<<<dim3(128, 2), 256, 0, stream>>>(interp, 256, feat1, 128,
                                                w_up1, w_up1 + (size_t)256 * 128, b_up1,
                                                fupa, 8192, 128, 1);
  hbar_kernel<<<4224, 256, 0, stream>>>(fupa, pos1, knn1, 4096, 128, 2, hbar);
  gemm_kernel<<<dim3(128, 2), 256, 0, stream>>>(fupa, 128, hbar, 132, w_upc1s, w_upc1e, nullptr,
                                                fup1, 8192, 128, 1);
  // --- up level 0: interp(fup1)->pos0, concat feat0, linear, edge conv ---
  three_nn_kernel<16><<<dim3(512, 2), 256, 0, stream>>>(pp0, pp1, 8192, 4096, nn0i, nn0w);
  interp_kernel<<<8192, 256, 0, stream>>>(fup1, nn0i, nn0w, 8192, 4096, 128, 2, interp);
  gemm_kernel<<<dim3(256, 1), 256, 0, stream>>>(interp, 128, feat0, 64,
                                                w_up0, w_up0 + (size_t)128 * 64, b_up0,
                                                fupa, 16384, 64, 1);
  hbar_kernel<<<4352, 256, 0, stream>>>(fupa, pos, knn0, 8192, 64, 2, hbar);
  gemm_kernel<<<dim3(256, 1), 256, 0, stream>>>(fupa, 64, hbar, 68, w_upc0s, w_upc0e, nullptr,
                                                fout, 16384, 64, 1);
  // --- final projection ---
  gemm_kernel<<<dim3(256, 2), 256, 0, stream>>>(fout, 64, nullptr, 0, w_out, nullptr, b_out,
                                                out, 16384, 128, 0);
}

// Round 8
// 5650.176 us; speedup vs baseline: 1.9688x; 1.0546x over previous
//
#include <hip/hip_runtime.h>
#include <cstdint>

typedef unsigned long long u64;

static __device__ __forceinline__ float leakyf(float v) { return v >= 0.f ? v : 0.2f * v; }

// ------------------------------------------------------------------
// DPP wave64 u64-max reduction (rocPRIM pattern: row_shr 1/2/4/8 + row_bcast15/31;
// lane 63 accumulates; readlane(63) broadcasts). bound_ctrl=false with old=x =>
// lanes without a source keep x; max(x,x)=x identity — exact. (R5/R7-validated.)
template<int CTRL>
static __device__ __forceinline__ u64 dpp_max_u64_step(u64 x)
{
  unsigned lo = (unsigned)x, hi = (unsigned)(x >> 32);
  unsigned ylo = (unsigned)__builtin_amdgcn_update_dpp((int)lo, (int)lo, CTRL, 0xF, 0xF, false);
  unsigned yhi = (unsigned)__builtin_amdgcn_update_dpp((int)hi, (int)hi, CTRL, 0xF, 0xF, false);
  u64 y = ((u64)yhi << 32) | (u64)ylo;
  return x > y ? x : y;
}
static __device__ __forceinline__ u64 wave64_max_u64(u64 x)
{
  x = dpp_max_u64_step<0x111>(x);
  x = dpp_max_u64_step<0x112>(x);
  x = dpp_max_u64_step<0x114>(x);
  x = dpp_max_u64_step<0x118>(x);
  x = dpp_max_u64_step<0x142>(x);
  x = dpp_max_u64_step<0x143>(x);
  unsigned lo = (unsigned)__builtin_amdgcn_readlane((int)(unsigned)x, 63);
  unsigned hi = (unsigned)__builtin_amdgcn_readlane((int)(unsigned)(x >> 32), 63);
  return ((u64)hi << 32) | (u64)lo;
}

// ------------------------------------------------------------------
// FPS body (exact, matches jax scan semantics). 256 threads, dense register update.
// KEY FIX vs R7: coordinate arrays are PINNED in VGPRs (asm) and spos is staged with
// a DIFFERENT index mapping than the register loads, so the compiler cannot
// rematerialize px/py/pz as per-iteration LDS reads (R7: 131KB LDS traffic/iter).
template<int N, int NPOINT>
static __device__ void fps_body(const float* __restrict__ P,
                                int* __restrict__ oi, float* __restrict__ op,
                                float4* __restrict__ opp,
                                float4* spos, u64* redk /* [2][4] flat */)
{
  constexpr int BLOCK = 256;
  constexpr int NPT = N / BLOCK;
  const int t = threadIdx.x;
  const int lane = t & 63;
  const int wv = t >> 6;

  // contiguous staging (thread t owns spos[t*NPT .. t*NPT+NPT)) — different
  // ownership than the strided register arrays below => no value-CSE/remat.
  for (int k = 0; k < NPT; ++k) {
    int i = t * NPT + k;
    float x = P[i*3+0], y = P[i*3+1], z = P[i*3+2];
    spos[i] = make_float4(x, y, z, (x*x + y*y) + z*z);
  }
  // strided register ownership: point i = t + j*256 (coalesced loads)
  float px[NPT], py[NPT], pz[NPT], dist[NPT];
#pragma unroll
  for (int j = 0; j < NPT; ++j) {
    int i = t + j * BLOCK;
    float x = P[i*3+0], y = P[i*3+1], z = P[i*3+2];
    px[j] = x; py[j] = y; pz[j] = z; dist[j] = 1e10f;
    asm volatile("" : "+v"(px[j]), "+v"(py[j]), "+v"(pz[j]));  // pin in VGPRs
  }
  if (t == 0) oi[0] = 0;
  __syncthreads();

  int far = 0;
  for (int it = 1; it < NPOINT; ++it) {
    const float4 c = spos[far];              // one b128 broadcast read
    if (t == ((it - 1) & (BLOCK - 1))) {     // emit sample it-1 (coords = current center)
      op[(it-1)*3+0] = c.x; op[(it-1)*3+1] = c.y; op[(it-1)*3+2] = c.z;
      opp[it-1] = c;
    }
    float bd = -1.f; unsigned biv = 0u;
#pragma unroll
    for (int j = 0; j < NPT; ++j) {
      float dx = px[j] - c.x, dy = py[j] - c.y, dz = pz[j] - c.z;
      float d  = fmaf(dz, dz, fmaf(dy, dy, dx * dx));
      float nd = fminf(dist[j], d);
      dist[j] = nd;
      bool bt = nd > bd;                     // strict >: ties keep earlier j = lower idx
      bd  = bt ? nd : bd;
      biv = bt ? (0xFFFFFFFFu - (unsigned)(t + j * BLOCK)) : biv;  // rematerializable
    }
    u64 key = ((u64)__float_as_uint(bd) << 32) | (u64)biv;
    key = wave64_max_u64(key);
    const int par = it & 1;
    if (lane == 0) redk[par*4 + wv] = key;
    __syncthreads();
    const ulonglong2 p01 = *reinterpret_cast<const ulonglong2*>(&redk[par*4 + 0]);
    const ulonglong2 p23 = *reinterpret_cast<const ulonglong2*>(&redk[par*4 + 2]);
    u64 k0 = p01.x > p01.y ? p01.x : p01.y;
    u64 k1 = p23.x > p23.y ? p23.x : p23.y;
    key = k0 > k1 ? k0 : k1;
    far = (int)(0xFFFFFFFFu - (unsigned)(key & 0xFFFFFFFFull));
    if (t == 0) oi[it] = far;
  }
  {
    const float4 c = spos[far];
    if (t == ((NPOINT - 1) & (BLOCK - 1))) {
      op[(NPOINT-1)*3+0] = c.x; op[(NPOINT-1)*3+1] = c.y; op[(NPOINT-1)*3+2] = c.z;
      opp[NPOINT-1] = c;
    }
  }
}

// ------------------------------------------------------------------
// Self-KNN body (K=16), RAW pos input (packs |p|^2 in-tile with the exact same
// association (x*x+y*y)+z*z as the original pack path => bit-identical distances).
// G=16 segments/query; sorted top-16 in registers; shfl_xor bitonic merge.
template<int G>
static __device__ void knn_body(const float* __restrict__ pos, int M,
                                int* __restrict__ out, float4* tile, int xb, int b)
{
  const float* P = pos + (size_t)b * M * 3;
  const int tid = threadIdx.x;
  constexpr int QPB = 256 / G;
  const int q = xb * QPB + tid / G;
  const int seg = tid % G;

  const float qx = P[q*3+0], qy = P[q*3+1], qz = P[q*3+2];
  const float qq = (qx*qx + qy*qy) + qz*qz;

  float a[16]; int id[16];
#pragma unroll
  for (int j = 0; j < 16; ++j) { a[j] = 3.4e38f; id[j] = 0x7fffffff; }

  for (int t0 = 0; t0 < M; t0 += 512) {
    __syncthreads();
    for (int i = tid; i < 512; i += 256) {
      int gi = t0 + i;
      float x = P[gi*3+0], y = P[gi*3+1], z = P[gi*3+2];
      tile[i] = make_float4(x, y, z, (x*x + y*y) + z*z);
    }
    __syncthreads();
#pragma unroll 4
    for (int i = seg; i < 512; i += G) {
      float4 c = tile[i];
      float d = (qq + c.w) - 2.f * ((qx*c.x + qy*c.y) + qz*c.z);
      int gi = t0 + i;
      if (d < a[15]) {
        bool cc[16];
#pragma unroll
        for (int j = 0; j < 16; ++j) cc[j] = d < a[j];
#pragma unroll
        for (int j = 15; j >= 1; --j) {
          a[j]  = cc[j-1] ? a[j-1]  : (cc[j] ? d  : a[j]);
          id[j] = cc[j-1] ? id[j-1] : (cc[j] ? gi : id[j]);
        }
        if (cc[0]) { a[0] = d; id[0] = gi; }
      }
    }
  }
#pragma unroll
  for (int s = G/2; s >= 1; s >>= 1) {
    float bd[16]; int bi[16];
#pragma unroll
    for (int j = 0; j < 16; ++j) { bd[j] = __shfl_xor(a[j], s); bi[j] = __shfl_xor(id[j], s); }
#pragma unroll
    for (int j = 0; j < 16; ++j) {
      float od = bd[15-j]; int ob = bi[15-j];
      bool take = (od < a[j]) || (od == a[j] && ob < id[j]);
      a[j]  = take ? od : a[j];
      id[j] = take ? ob : id[j];
    }
#pragma unroll
    for (int st = 8; st >= 1; st >>= 1) {
#pragma unroll
      for (int j = 0; j < 16; ++j) {
        if ((j & st) == 0) {
          const int j2 = j + st;
          bool sw = (a[j2] < a[j]) || (a[j2] == a[j] && id[j2] < id[j]);
          float lod = sw ? a[j2] : a[j];  int loi = sw ? id[j2] : id[j];
          float hid = sw ? a[j]  : a[j2]; int hii = sw ? id[j]  : id[j2];
          a[j] = lod; id[j] = loi; a[j2] = hid; id[j2] = hii;
        }
      }
    }
  }
  if (seg == 0) {
    int* opp = out + ((size_t)b * M + q) * 16;
#pragma unroll
    for (int j = 0; j < 16; ++j) opp[j] = id[j];
  }
}

__global__ __launch_bounds__(256) void knn_kernel(const float* __restrict__ pos, int M,
                                                  int* __restrict__ out)
{
  __shared__ float4 tile[512];
  knn_body<16>(pos, M, out, tile, blockIdx.x, blockIdx.y);
}

// ------------------------------------------------------------------
// three_nn body + weights (packed float4 inputs).
template<int G>
static __device__ void three_nn_body(const float4* __restrict__ qpp,
                                     const float4* __restrict__ kpp,
                                     int Mq, int Mk,
                                     int* __restrict__ oidx, float* __restrict__ ow,
                                     float4* tile, int xb, int b)
{
  const float4* Q  = qpp + (size_t)b * Mq;
  const float4* Kp = kpp + (size_t)b * Mk;
  const int tid = threadIdx.x;
  constexpr int QPB = 256 / G;
  const int q = xb * QPB + tid / G;
  const int seg = tid % G;

  const float4 qp = Q[q];
  const float qx = qp.x, qy = qp.y, qz = qp.z, qq = qp.w;

  float a[4]; int id[4];
#pragma unroll
  for (int j = 0; j < 4; ++j) { a[j] = 3.4e38f; id[j] = 0x7fffffff; }

  for (int t0 = 0; t0 < Mk; t0 += 512) {
    __syncthreads();
    tile[tid]       = Kp[t0 + tid];
    tile[tid + 256] = Kp[t0 + tid + 256];
    __syncthreads();
#pragma unroll 4
    for (int i = seg; i < 512; i += G) {
      float4 c = tile[i];
      float d = (qq + c.w) - 2.f * ((qx*c.x + qy*c.y) + qz*c.z);
      int gi = t0 + i;
      if (d < a[3]) {
        bool c0 = d < a[0], c1 = d < a[1], c2 = d < a[2];
        a[3]  = c2 ? a[2]  : d;                id[3] = c2 ? id[2] : gi;
        a[2]  = c1 ? a[1]  : (c2 ? d  : a[2]); id[2] = c1 ? id[1] : (c2 ? gi : id[2]);
        a[1]  = c0 ? a[0]  : (c1 ? d  : a[1]); id[1] = c0 ? id[0] : (c1 ? gi : id[1]);
        if (c0) { a[0] = d; id[0] = gi; }
      }
    }
  }
#pragma unroll
  for (int s = G/2; s >= 1; s >>= 1) {
    float bd[4]; int bi[4];
#pragma unroll
    for (int j = 0; j < 4; ++j) { bd[j] = __shfl_xor(a[j], s); bi[j] = __shfl_xor(id[j], s); }
#pragma unroll
    for (int j = 0; j < 4; ++j) {
      float od = bd[3-j]; int ob = bi[3-j];
      bool take = (od < a[j]) || (od == a[j] && ob < id[j]);
      a[j]  = take ? od : a[j];
      id[j] = take ? ob : id[j];
    }
#pragma unroll
    for (int st = 2; st >= 1; st >>= 1) {
#pragma unroll
      for (int j = 0; j < 4; ++j) {
        if ((j & st) == 0) {
          const int j2 = j + st;
          bool sw = (a[j2] < a[j]) || (a[j2] == a[j] && id[j2] < id[j]);
          float lod = sw ? a[j2] : a[j];  int loi = sw ? id[j2] : id[j];
          float hid = sw ? a[j]  : a[j2]; int hii = sw ? id[j]  : id[j2];
          a[j] = lod; id[j] = loi; a[j2] = hid; id[j2] = hii;
        }
      }
    }
  }
  if (seg == 0) {
    float d0 = fmaxf(a[0], 0.f), d1 = fmaxf(a[1], 0.f), d2 = fmaxf(a[2], 0.f);
    float r0 = 1.f/(d0 + 1e-8f), r1 = 1.f/(d1 + 1e-8f), r2 = 1.f/(d2 + 1e-8f);
    float s = (r0 + r1) + r2;
    size_t o = ((size_t)b * Mq + q) * 3;
    oidx[o+0] = id[0]; oidx[o+1] = id[1]; oidx[o+2] = id[2];
    ow[o+0] = r0/s; ow[o+1] = r1/s; ow[o+2] = r2/s;
  }
}

__global__ __launch_bounds__(256) void three_nn_kernel(const float4* __restrict__ qpp,
                                                       const float4* __restrict__ kpp,
                                                       int Mq, int Mk,
                                                       int* __restrict__ oidx, float* __restrict__ ow)
{
  __shared__ float4 tile[512];
  three_nn_body<16>(qpp, kpp, Mq, Mk, oidx, ow, tile, blockIdx.x, blockIdx.y);
}

// ------------------------------------------------------------------
// Edge-conv neighbor mean (elementwise over B*M*(C+4); no LDS)
static __device__ void hbar_body(const float* __restrict__ x, const float* __restrict__ pos,
                                 const int* __restrict__ idx, int Mlvl, int C, int B,
                                 float* __restrict__ out, int e)
{
  const int Ct = C + 4;
  const int tot = B * Mlvl * Ct;
  if (e >= tot) return;
  const int c  = e % Ct;
  const int p  = e / Ct;
  const int b  = p / Mlvl;
  const int lm = p % Mlvl;
  const int* ip = idx + (size_t)p * 16;
  float s = 0.f;
  if (c < C) {
    const float* xb = x + (size_t)b * Mlvl * C;
#pragma unroll 4
    for (int k = 0; k < 16; ++k) s += xb[(size_t)ip[k] * C + c];
  } else if (c < C + 3) {
    const int dd = c - C;
    const float* pb = pos + (size_t)b * Mlvl * 3;
    const float pc = pb[lm*3 + dd];
#pragma unroll 4
    for (int k = 0; k < 16; ++k) s += pc - pb[ip[k]*3 + dd];
  } else {
    const float* pb = pos + (size_t)b * Mlvl * 3;
    const float px = pb[lm*3+0], py = pb[lm*3+1], pz = pb[lm*3+2];
#pragma unroll 4
    for (int k = 0; k < 16; ++k) {
      int n = ip[k];
      float dx = px - pb[n*3+0], dy = py - pb[n*3+1], dz = pz - pb[n*3+2];
      s += (dx*dx + dy*dy) + dz*dz;
    }
  }
  out[e] = s * 0.0625f;
}

__global__ void hbar_kernel(const float* __restrict__ x, const float* __restrict__ pos,
                            const int* __restrict__ idx, int Mlvl, int C, int B,
                            float* __restrict__ out)
{
  hbar_body(x, pos, idx, Mlvl, C, B, out, blockIdx.x * 256 + threadIdx.x);
}

// ------------------------------------------------------------------
// Fused dispatch 1: fps level-1 (blocks 0-1) || knn0 (blocks 2-1025) || pack pp0.
// All parts depend ONLY on inputs (pos) — no intra-dispatch dependencies.
// fps blocks are first in dispatch order => start immediately on CU0/CU1.
__global__ __launch_bounds__(256, 1) void fused1_kernel(const float* __restrict__ pos,
    int* __restrict__ idx1, float* __restrict__ pos1, float4* __restrict__ pp1,
    float4* __restrict__ pp0, int* __restrict__ knn0)
{
  __shared__ __align__(16) char sm[8192 * 16 + 64];
  const int blk = blockIdx.x;
  if (blk < 2) {
    fps_body<8192, 4096>(pos + (size_t)blk * 8192 * 3,
                         idx1 + (size_t)blk * 4096,
                         pos1 + (size_t)blk * 4096 * 3,
                         pp1 + (size_t)blk * 4096,
                         (float4*)sm, (u64*)(sm + 8192 * 16));
  } else if (blk < 1026) {
    const int i = blk - 2;
    knn_body<16>(pos, 8192, knn0, (float4*)sm, i & 511, i >> 9);
  } else {
    const int i = (blk - 1026) * 256 + threadIdx.x;
    if (i < 2 * 8192) {
      float x = pos[i*3+0], y = pos[i*3+1], z = pos[i*3+2];
      pp0[i] = make_float4(x, y, z, (x*x + y*y) + z*z);
    }
  }
}

// Fused dispatch 2: fps level-2 (blocks 0-1) || knn1 || hbar0 || three_nn0.
// Inputs: pos1/pp1/idx-free products of fused1; knn0 from fused1. No intra-deps.
__global__ __launch_bounds__(256, 1) void fused2_kernel(const float* __restrict__ pos,
    const float* __restrict__ pos1, const float* __restrict__ x,
    const int* __restrict__ knn0, float* __restrict__ hbar,
    int* __restrict__ idx2, float* __restrict__ pos2, float4* __restrict__ pp2,
    int* __restrict__ knn1,
    const float4* __restrict__ pp0, const float4* __restrict__ pp1,
    int* __restrict__ nn0i, float* __restrict__ nn0w)
{
  __shared__ __align__(16) char sm[4096 * 16 + 64];
  const int blk = blockIdx.x;
  if (blk < 2) {
    fps_body<4096, 2048>(pos1 + (size_t)blk * 4096 * 3,
                         idx2 + (size_t)blk * 2048,
                         pos2 + (size_t)blk * 2048 * 3,
                         pp2 + (size_t)blk * 2048,
                         (float4*)sm, (u64*)(sm + 4096 * 16));
  } else if (blk < 514) {
    const int i = blk - 2;
    knn_body<16>(pos1, 4096, knn1, (float4*)sm, i & 255, i >> 8);
  } else if (blk < 1026) {
    const int e = (blk - 514) * 256 + threadIdx.x;
    hbar_body(x, pos, knn0, 8192, 4, 2, hbar, e);
  } else {
    const int i = blk - 1026;
    three_nn_body<16>(pp0, pp1, 8192, 4096, nn0i, nn0w, (float4*)sm, i & 511, i >> 9);
  }
}

// ------------------------------------------------------------------
__global__ void interp_kernel(const float* __restrict__ f, const int* __restrict__ nidx,
                              const float* __restrict__ nw, int Mq, int Msub, int C, int B,
                              float* __restrict__ out)
{
  const int tot = B * Mq * C;
  int e = blockIdx.x * 256 + threadIdx.x;
  if (e >= tot) return;
  const int c = e % C;
  const int p = e / C;
  const int b = p / Mq;
  const float* fb = f + (size_t)b * Msub * C;
  const int* ip   = nidx + (size_t)p * 3;
  const float* wp = nw   + (size_t)p * 3;
  out[e] = (wp[0] * fb[(size_t)ip[0]*C + c] + wp[1] * fb[(size_t)ip[1]*C + c])
         +  wp[2] * fb[(size_t)ip[2]*C + c];
}

// ------------------------------------------------------------------
__global__ void gather_kernel(const float* __restrict__ src, const int* __restrict__ idx,
                              int Mq, int Msrc, int C, int B, float* __restrict__ dst)
{
  const int tot = B * Mq * C;
  int e = blockIdx.x * 256 + threadIdx.x;
  if (e >= tot) return;
  const int c = e % C;
  const int p = e / C;
  const int b = p / Mq;
  dst[e] = src[((size_t)b * Msrc + idx[p]) * C + c];
}

// ------------------------------------------------------------------
// Fused GEMM: out[M,F] = act( A[M,Ka]@W1[Ka,F] + B2[M,Kb]@W2[Kb,F] + bias )
__global__ __launch_bounds__(256) void gemm_kernel(const float* __restrict__ A, int Ka,
                                                   const float* __restrict__ B2, int Kb,
                                                   const float* __restrict__ W1,
                                                   const float* __restrict__ W2,
                                                   const float* __restrict__ bias,
                                                   float* __restrict__ out,
                                                   int M, int F, int act)
{
  __shared__ __align__(16) float As[16][64];
  __shared__ __align__(16) float Ws[16][64];
  const int tid  = threadIdx.x;
  const int row0 = blockIdx.x * 64;
  const int col0 = blockIdx.y * 64;
  const int tx = tid & 15, ty = tid >> 4;
  const int K = Ka + Kb;
  float acc[4][4] = {};
  for (int k0 = 0; k0 < K; k0 += 16) {
#pragma unroll
    for (int i = 0; i < 4; ++i) {
      int e = tid + i * 256;
      int m = e & 63, kk = e >> 6;
      int k = k0 + kk;
      float v = 0.f;
      if (k < Ka)     v = A [(size_t)(row0 + m) * Ka + k];
      else if (k < K) v = B2[(size_t)(row0 + m) * Kb + (k - Ka)];
      As[kk][m] = v;
      float wv = 0.f;
      if (k < Ka)     wv = W1[(size_t)k * F + col0 + m];
      else if (k < K) wv = W2[(size_t)(k - Ka) * F + col0 + m];
      Ws[kk][m] = wv;
    }
    __syncthreads();
#pragma unroll
    for (int kk = 0; kk < 16; ++kk) {
      const float4 a4 = *reinterpret_cast<const float4*>(&As[kk][ty * 4]);
      const float4 b4 = *reinterpret_cast<const float4*>(&Ws[kk][tx * 4]);
      const float av[4] = {a4.x, a4.y, a4.z, a4.w};
      const float bv[4] = {b4.x, b4.y, b4.z, b4.w};
#pragma unroll
      for (int i2 = 0; i2 < 4; ++i2)
#pragma unroll
        for (int j2 = 0; j2 < 4; ++j2)
          acc[i2][j2] = fmaf(av[i2], bv[j2], acc[i2][j2]);
    }
    __syncthreads();
  }
#pragma unroll
  for (int i2 = 0; i2 < 4; ++i2) {
    int r = row0 + ty * 4 + i2;
#pragma unroll
    for (int j2 = 0; j2 < 4; ++j2) {
      int cc = col0 + tx * 4 + j2;
      float v = acc[i2][j2];
      if (bias) v += bias[cc];
      if (act)  v = leakyf(v);
      out[(size_t)r * F + cc] = v;
    }
  }
}

// ------------------------------------------------------------------
extern "C" void kernel_launch(void* const* d_in, const int* in_sizes, int n_in,
                              void* d_out, int out_size, void* d_ws, size_t ws_size,
                              hipStream_t stream)
{
  (void)in_sizes; (void)n_in; (void)out_size; (void)ws_size;
  const float* x          = (const float*)d_in[0];   // [2,8192,4]
  const float* pos        = (const float*)d_in[1];   // [2,8192,3]
  const float* w_self0    = (const float*)d_in[2];   // [4,64]
  const float* w_edge0    = (const float*)d_in[3];   // [8,64]
  const float* w_self1    = (const float*)d_in[4];   // [64,128]
  const float* w_edge1    = (const float*)d_in[5];   // [68,128]
  const float* w_self2    = (const float*)d_in[6];   // [128,256]
  const float* w_edge2    = (const float*)d_in[7];   // [132,256]
  const float* w_up1      = (const float*)d_in[8];   // [384,128]
  const float* b_up1      = (const float*)d_in[9];   // [128]
  const float* w_upc1s    = (const float*)d_in[10];  // [128,128]
  const float* w_upc1e    = (const float*)d_in[11];  // [132,128]
  const float* w_up0      = (const float*)d_in[12];  // [192,64]
  const float* b_up0      = (const float*)d_in[13];  // [64]
  const float* w_upc0s    = (const float*)d_in[14];  // [64,64]
  const float* w_upc0e    = (const float*)d_in[15];  // [68,64]
  const float* w_out      = (const float*)d_in[16];  // [64,128]
  const float* b_out      = (const float*)d_in[17];  // [128]
  float* out = (float*)d_out;                        // [2,8192,128]

  char* ws = (char*)d_ws;
  size_t off = 0;
  auto alloc = [&](size_t nbytes) -> void* {
    off = (off + 255) & ~(size_t)255;
    void* p = ws + off;
    off += nbytes;
    return p;
  };
  int*    knn0   = (int*)   alloc((size_t)2*8192*16*4);
  int*    knn1   = (int*)   alloc((size_t)2*4096*16*4);
  int*    knn2   = (int*)   alloc((size_t)2*2048*16*4);
  int*    idx1   = (int*)   alloc((size_t)2*4096*4);
  int*    idx2   = (int*)   alloc((size_t)2*2048*4);
  float*  pos1   = (float*) alloc((size_t)2*4096*3*4);
  float*  pos2   = (float*) alloc((size_t)2*2048*3*4);
  float4* pp0    = (float4*)alloc((size_t)2*8192*16);
  float4* pp1    = (float4*)alloc((size_t)2*4096*16);
  float4* pp2    = (float4*)alloc((size_t)2*2048*16);
  float*  feat0  = (float*) alloc((size_t)2*8192*64*4);
  float*  feat0g = (float*) alloc((size_t)2*4096*64*4);
  float*  feat1  = (float*) alloc((size_t)2*4096*128*4);
  float*  feat1g = (float*) alloc((size_t)2*2048*128*4);
  float*  feat2  = (float*) alloc((size_t)2*2048*256*4);
  int*    nn1i   = (int*)   alloc((size_t)2*4096*3*4);
  float*  nn1w   = (float*) alloc((size_t)2*4096*3*4);
  int*    nn0i   = (int*)   alloc((size_t)2*8192*3*4);
  float*  nn0w   = (float*) alloc((size_t)2*8192*3*4);
  float*  interp = (float*) alloc((size_t)2*4096*256*4);  // reused for interp0 (same size)
  float*  hbar   = (float*) alloc((size_t)2*8192*68*4);   // max of all hbar stages
  float*  fupa   = (float*) alloc((size_t)2*4096*128*4);  // fup1a, later fup0a (same size)
  float*  fup1   = (float*) alloc((size_t)2*4096*128*4);
  float*  fout   = (float*) alloc((size_t)2*8192*64*4);

  // D1: fps1 || knn0 || pack(pp0)
  fused1_kernel<<<1090, 256, 0, stream>>>(pos, idx1, pos1, pp1, pp0, knn0);
  // D2: fps2 || knn1 || hbar0 || three_nn0
  fused2_kernel<<<2050, 256, 0, stream>>>(pos, pos1, x, knn0, hbar,
                                          idx2, pos2, pp2, knn1, pp0, pp1, nn0i, nn0w);
  // level-0 edge conv finish
  gemm_kernel<<<dim3(256, 1), 256, 0, stream>>>(x, 4, hbar, 8, w_self0, w_edge0, nullptr,
                                                feat0, 16384, 64, 1);
  // level-1 chain
  gather_kernel<<<2048, 256, 0, stream>>>(feat0, idx1, 4096, 8192, 64, 2, feat0g);
  hbar_kernel<<<2176, 256, 0, stream>>>(feat0g, pos1, knn1, 4096, 64, 2, hbar);
  gemm_kernel<<<dim3(128, 2), 256, 0, stream>>>(feat0g, 64, hbar, 68, w_self1, w_edge1, nullptr,
                                                feat1, 8192, 128, 1);
  // level-2 chain
  gather_kernel<<<2048, 256, 0, stream>>>(feat1, idx2, 2048, 4096, 128, 2, feat1g);
  knn_kernel<<<dim3(128, 2), 256, 0, stream>>>(pos2, 2048, knn2);
  hbar_kernel<<<2112, 256, 0, stream>>>(feat1g, pos2, knn2, 2048, 128, 2, hbar);
  gemm_kernel<<<dim3(64, 4), 256, 0, stream>>>(feat1g, 128, hbar, 132, w_self2, w_edge2, nullptr,
                                               feat2, 4096, 256, 1);
  // up level 1
  three_nn_kernel<<<dim3(256, 2), 256, 0, stream>>>(pp1, pp2, 4096, 2048, nn1i, nn1w);
  interp_kernel<<<8192, 256, 0, stream>>>(feat2, nn1i, nn1w, 4096, 2048, 256, 2, interp);
  gemm_kernel<<<dim3(128, 2), 256, 0, stream>>>(interp, 256, feat1, 128,
                                                w_up1, w_up1 + (size_t)256 * 128, b_up1,
                                                fupa, 8192, 128, 1);
  hbar_kernel<<<4224, 256, 0, stream>>>(fupa, pos1, knn1, 4096, 128, 2, hbar);
  gemm_kernel<<<dim3(128, 2), 256, 0, stream>>>(fupa, 128, hbar, 132, w_upc1s, w_upc1e, nullptr,
                                                fup1, 8192, 128, 1);
  // up level 0 (nn0i/nn0w already computed in fused2)
  interp_kernel<<<8192, 256, 0, stream>>>(fup1, nn0i, nn0w, 8192, 4096, 128, 2, interp);
  gemm_kernel<<<dim3(256, 1), 256, 0, stream>>>(interp, 128, feat0, 64,
                                                w_up0, w_up0 + (size_t)128 * 64, b_up0,
                                                fupa, 16384, 64, 1);
  hbar_kernel<<<4352, 256, 0, stream>>>(fupa, pos, knn0, 8192, 64, 2, hbar);
  gemm_kernel<<<dim3(256, 1), 256, 0, stream>>>(fupa, 64, hbar, 68, w_upc0s, w_upc0e, nullptr,
                                                fout, 16384, 64, 1);
  // final projection
  gemm_kernel<<<dim3(256, 2), 256, 0, stream>>>(fout, 64, nullptr, 0, w_out, nullptr, b_out,
                                                out, 16384, 128, 0);
}

// Round 9
// 5402.059 us; speedup vs baseline: 2.0592x; 1.0459x over previous
//
#include <hip/hip_runtime.h>
#include <cstdint>

typedef unsigned long long u64;

static __device__ __forceinline__ float leakyf(float v) { return v >= 0.f ? v : 0.2f * v; }

// ------------------------------------------------------------------
// DPP wave64 u64-max reduction (rocPRIM pattern: row_shr 1/2/4/8 + row_bcast15/31;
// lane 63 accumulates; readlane(63) broadcasts). bound_ctrl=false with old=x =>
// lanes without a source keep x; max(x,x)=x identity — exact. (R5/R7/R8-validated.)
template<int CTRL>
static __device__ __forceinline__ u64 dpp_max_u64_step(u64 x)
{
  unsigned lo = (unsigned)x, hi = (unsigned)(x >> 32);
  unsigned ylo = (unsigned)__builtin_amdgcn_update_dpp((int)lo, (int)lo, CTRL, 0xF, 0xF, false);
  unsigned yhi = (unsigned)__builtin_amdgcn_update_dpp((int)hi, (int)hi, CTRL, 0xF, 0xF, false);
  u64 y = ((u64)yhi << 32) | (u64)ylo;
  return x > y ? x : y;
}
static __device__ __forceinline__ u64 wave64_max_u64(u64 x)
{
  x = dpp_max_u64_step<0x111>(x);
  x = dpp_max_u64_step<0x112>(x);
  x = dpp_max_u64_step<0x114>(x);
  x = dpp_max_u64_step<0x118>(x);
  x = dpp_max_u64_step<0x142>(x);
  x = dpp_max_u64_step<0x143>(x);
  unsigned lo = (unsigned)__builtin_amdgcn_readlane((int)(unsigned)x, 63);
  unsigned hi = (unsigned)__builtin_amdgcn_readlane((int)(unsigned)(x >> 32), 63);
  return ((u64)hi << 32) | (u64)lo;
}

// ------------------------------------------------------------------
// FPS body (exact, matches jax scan semantics). NT threads, dense register update.
// NT sized so px/py/pz/dist (4*N/NT regs) FIT IN VGPRS (R8 lesson: NPT=32 => spill,
// ~450 extra cyc/iter of register-restore traffic; NPT<=16 fits).
// Per iter: LDS b128 broadcast of center; per-thread scan (strict > keeps lowest idx);
// u64 key (f32 bits of d || 0xFFFFFFFF-idx) -> single 6-step DPP u64 max per wave;
// NW partials in LDS (double-buffered), 1 barrier, combine via b128 pairs.
// Selection bit-identical to R5/R7/R8 (associative exact lexmax; partition-free).
template<int N, int NPOINT, int NT>
static __device__ void fps_body(const float* __restrict__ P,
                                int* __restrict__ oi, float* __restrict__ op,
                                float4* __restrict__ opp,
                                float4* spos, u64* redk /* [2][NW] flat, 16B aligned */)
{
  constexpr int NPT = N / NT;
  constexpr int NW = NT / 64;
  const int t = threadIdx.x;
  const int lane = t & 63;
  const int wv = t >> 6;

  // contiguous staging (thread t owns spos[t*NPT ..)) — different ownership than
  // the strided register arrays below => no value-CSE/remat.
  for (int k = 0; k < NPT; ++k) {
    int i = t * NPT + k;
    float x = P[i*3+0], y = P[i*3+1], z = P[i*3+2];
    spos[i] = make_float4(x, y, z, (x*x + y*y) + z*z);
  }
  // strided register ownership: point i = t + j*NT (coalesced loads)
  float px[NPT], py[NPT], pz[NPT], dist[NPT];
#pragma unroll
  for (int j = 0; j < NPT; ++j) {
    int i = t + j * NT;
    float x = P[i*3+0], y = P[i*3+1], z = P[i*3+2];
    px[j] = x; py[j] = y; pz[j] = z; dist[j] = 1e10f;
    asm volatile("" : "+v"(px[j]), "+v"(py[j]), "+v"(pz[j]));  // pin in VGPRs
  }
  if (t == 0) oi[0] = 0;
  __syncthreads();

  int far = 0;
  for (int it = 1; it < NPOINT; ++it) {
    const float4 c = spos[far];              // one b128 broadcast read
    if (t == ((it - 1) & (NT - 1))) {        // emit sample it-1 (coords = current center)
      op[(it-1)*3+0] = c.x; op[(it-1)*3+1] = c.y; op[(it-1)*3+2] = c.z;
      opp[it-1] = c;
    }
    float bd = -1.f; unsigned biv = 0u;
#pragma unroll
    for (int j = 0; j < NPT; ++j) {
      float dx = px[j] - c.x, dy = py[j] - c.y, dz = pz[j] - c.z;
      float d  = fmaf(dz, dz, fmaf(dy, dy, dx * dx));
      float nd = fminf(dist[j], d);
      dist[j] = nd;
      bool bt = nd > bd;                     // strict >: ties keep earlier j = lower idx
      bd  = bt ? nd : bd;
      biv = bt ? (0xFFFFFFFFu - (unsigned)(t + j * NT)) : biv;  // rematerializable
    }
    u64 key = ((u64)__float_as_uint(bd) << 32) | (u64)biv;
    key = wave64_max_u64(key);
    const int par = it & 1;
    if (lane == 0) redk[par*NW + wv] = key;
    __syncthreads();
#pragma unroll
    for (int w2 = 0; w2 < NW / 2; ++w2) {
      const ulonglong2 p = *reinterpret_cast<const ulonglong2*>(&redk[par*NW + 2*w2]);
      u64 m = p.x > p.y ? p.x : p.y;
      if (m > key) key = m;
    }
    far = (int)(0xFFFFFFFFu - (unsigned)(key & 0xFFFFFFFFull));
    if (t == 0) oi[it] = far;
  }
  {
    const float4 c = spos[far];
    if (t == ((NPOINT - 1) & (NT - 1))) {
      op[(NPOINT-1)*3+0] = c.x; op[(NPOINT-1)*3+1] = c.y; op[(NPOINT-1)*3+2] = c.z;
      opp[NPOINT-1] = c;
    }
  }
}

// ------------------------------------------------------------------
// Self-KNN body (K=16), RAW pos input (packs |p|^2 in-tile with the exact same
// association (x*x+y*y)+z*z => bit-identical distances). NT threads, G=16
// segments/query; sorted top-16 in registers; shfl_xor bitonic merge (intra-wave:
// a query's 16 threads are contiguous, 16 | 64).
template<int NT, int G>
static __device__ void knn_body(const float* __restrict__ pos, int M,
                                int* __restrict__ out, float4* tile, int xb, int b)
{
  const float* P = pos + (size_t)b * M * 3;
  const int tid = threadIdx.x;
  constexpr int QPB = NT / G;
  const int q = xb * QPB + tid / G;
  const int seg = tid % G;

  const float qx = P[q*3+0], qy = P[q*3+1], qz = P[q*3+2];
  const float qq = (qx*qx + qy*qy) + qz*qz;

  float a[16]; int id[16];
#pragma unroll
  for (int j = 0; j < 16; ++j) { a[j] = 3.4e38f; id[j] = 0x7fffffff; }

  for (int t0 = 0; t0 < M; t0 += 512) {
    __syncthreads();
    for (int i = tid; i < 512; i += NT) {
      int gi = t0 + i;
      float x = P[gi*3+0], y = P[gi*3+1], z = P[gi*3+2];
      tile[i] = make_float4(x, y, z, (x*x + y*y) + z*z);
    }
    __syncthreads();
#pragma unroll 4
    for (int i = seg; i < 512; i += G) {
      float4 c = tile[i];
      float d = (qq + c.w) - 2.f * ((qx*c.x + qy*c.y) + qz*c.z);
      int gi = t0 + i;
      if (d < a[15]) {
        bool cc[16];
#pragma unroll
        for (int j = 0; j < 16; ++j) cc[j] = d < a[j];
#pragma unroll
        for (int j = 15; j >= 1; --j) {
          a[j]  = cc[j-1] ? a[j-1]  : (cc[j] ? d  : a[j]);
          id[j] = cc[j-1] ? id[j-1] : (cc[j] ? gi : id[j]);
        }
        if (cc[0]) { a[0] = d; id[0] = gi; }
      }
    }
  }
#pragma unroll
  for (int s = G/2; s >= 1; s >>= 1) {
    float bd[16]; int bi[16];
#pragma unroll
    for (int j = 0; j < 16; ++j) { bd[j] = __shfl_xor(a[j], s); bi[j] = __shfl_xor(id[j], s); }
#pragma unroll
    for (int j = 0; j < 16; ++j) {
      float od = bd[15-j]; int ob = bi[15-j];
      bool take = (od < a[j]) || (od == a[j] && ob < id[j]);
      a[j]  = take ? od : a[j];
      id[j] = take ? ob : id[j];
    }
#pragma unroll
    for (int st = 8; st >= 1; st >>= 1) {
#pragma unroll
      for (int j = 0; j < 16; ++j) {
        if ((j & st) == 0) {
          const int j2 = j + st;
          bool sw = (a[j2] < a[j]) || (a[j2] == a[j] && id[j2] < id[j]);
          float lod = sw ? a[j2] : a[j];  int loi = sw ? id[j2] : id[j];
          float hid = sw ? a[j]  : a[j2]; int hii = sw ? id[j]  : id[j2];
          a[j] = lod; id[j] = loi; a[j2] = hid; id[j2] = hii;
        }
      }
    }
  }
  if (seg == 0) {
    int* opp = out + ((size_t)b * M + q) * 16;
#pragma unroll
    for (int j = 0; j < 16; ++j) opp[j] = id[j];
  }
}

__global__ __launch_bounds__(256) void knn_kernel(const float* __restrict__ pos, int M,
                                                  int* __restrict__ out)
{
  __shared__ float4 tile[512];
  knn_body<256, 16>(pos, M, out, tile, blockIdx.x, blockIdx.y);
}

// ------------------------------------------------------------------
// three_nn body + weights (packed float4 inputs).
template<int NT, int G>
static __device__ void three_nn_body(const float4* __restrict__ qpp,
                                     const float4* __restrict__ kpp,
                                     int Mq, int Mk,
                                     int* __restrict__ oidx, float* __restrict__ ow,
                                     float4* tile, int xb, int b)
{
  const float4* Q  = qpp + (size_t)b * Mq;
  const float4* Kp = kpp + (size_t)b * Mk;
  const int tid = threadIdx.x;
  constexpr int QPB = NT / G;
  const int q = xb * QPB + tid / G;
  const int seg = tid % G;

  const float4 qp = Q[q];
  const float qx = qp.x, qy = qp.y, qz = qp.z, qq = qp.w;

  float a[4]; int id[4];
#pragma unroll
  for (int j = 0; j < 4; ++j) { a[j] = 3.4e38f; id[j] = 0x7fffffff; }

  for (int t0 = 0; t0 < Mk; t0 += 512) {
    __syncthreads();
    for (int i = tid; i < 512; i += NT) tile[i] = Kp[t0 + i];
    __syncthreads();
#pragma unroll 4
    for (int i = seg; i < 512; i += G) {
      float4 c = tile[i];
      float d = (qq + c.w) - 2.f * ((qx*c.x + qy*c.y) + qz*c.z);
      int gi = t0 + i;
      if (d < a[3]) {
        bool c0 = d < a[0], c1 = d < a[1], c2 = d < a[2];
        a[3]  = c2 ? a[2]  : d;                id[3] = c2 ? id[2] : gi;
        a[2]  = c1 ? a[1]  : (c2 ? d  : a[2]); id[2] = c1 ? id[1] : (c2 ? gi : id[2]);
        a[1]  = c0 ? a[0]  : (c1 ? d  : a[1]); id[1] = c0 ? id[0] : (c1 ? gi : id[1]);
        if (c0) { a[0] = d; id[0] = gi; }
      }
    }
  }
#pragma unroll
  for (int s = G/2; s >= 1; s >>= 1) {
    float bd[4]; int bi[4];
#pragma unroll
    for (int j = 0; j < 4; ++j) { bd[j] = __shfl_xor(a[j], s); bi[j] = __shfl_xor(id[j], s); }
#pragma unroll
    for (int j = 0; j < 4; ++j) {
      float od = bd[3-j]; int ob = bi[3-j];
      bool take = (od < a[j]) || (od == a[j] && ob < id[j]);
      a[j]  = take ? od : a[j];
      id[j] = take ? ob : id[j];
    }
#pragma unroll
    for (int st = 2; st >= 1; st >>= 1) {
#pragma unroll
      for (int j = 0; j < 4; ++j) {
        if ((j & st) == 0) {
          const int j2 = j + st;
          bool sw = (a[j2] < a[j]) || (a[j2] == a[j] && id[j2] < id[j]);
          float lod = sw ? a[j2] : a[j];  int loi = sw ? id[j2] : id[j];
          float hid = sw ? a[j]  : a[j2]; int hii = sw ? id[j]  : id[j2];
          a[j] = lod; id[j] = loi; a[j2] = hid; id[j2] = hii;
        }
      }
    }
  }
  if (seg == 0) {
    float d0 = fmaxf(a[0], 0.f), d1 = fmaxf(a[1], 0.f), d2 = fmaxf(a[2], 0.f);
    float r0 = 1.f/(d0 + 1e-8f), r1 = 1.f/(d1 + 1e-8f), r2 = 1.f/(d2 + 1e-8f);
    float s = (r0 + r1) + r2;
    size_t o = ((size_t)b * Mq + q) * 3;
    oidx[o+0] = id[0]; oidx[o+1] = id[1]; oidx[o+2] = id[2];
    ow[o+0] = r0/s; ow[o+1] = r1/s; ow[o+2] = r2/s;
  }
}

__global__ __launch_bounds__(256) void three_nn_kernel(const float4* __restrict__ qpp,
                                                       const float4* __restrict__ kpp,
                                                       int Mq, int Mk,
                                                       int* __restrict__ oidx, float* __restrict__ ow)
{
  __shared__ float4 tile[512];
  three_nn_body<256, 16>(qpp, kpp, Mq, Mk, oidx, ow, tile, blockIdx.x, blockIdx.y);
}

// ------------------------------------------------------------------
// Edge-conv neighbor mean (elementwise over B*M*(C+4); no LDS)
static __device__ void hbar_body(const float* __restrict__ x, const float* __restrict__ pos,
                                 const int* __restrict__ idx, int Mlvl, int C, int B,
                                 float* __restrict__ out, int e)
{
  const int Ct = C + 4;
  const int tot = B * Mlvl * Ct;
  if (e >= tot) return;
  const int c  = e % Ct;
  const int p  = e / Ct;
  const int b  = p / Mlvl;
  const int lm = p % Mlvl;
  const int* ip = idx + (size_t)p * 16;
  float s = 0.f;
  if (c < C) {
    const float* xb = x + (size_t)b * Mlvl * C;
#pragma unroll 4
    for (int k = 0; k < 16; ++k) s += xb[(size_t)ip[k] * C + c];
  } else if (c < C + 3) {
    const int dd = c - C;
    const float* pb = pos + (size_t)b * Mlvl * 3;
    const float pc = pb[lm*3 + dd];
#pragma unroll 4
    for (int k = 0; k < 16; ++k) s += pc - pb[ip[k]*3 + dd];
  } else {
    const float* pb = pos + (size_t)b * Mlvl * 3;
    const float px = pb[lm*3+0], py = pb[lm*3+1], pz = pb[lm*3+2];
#pragma unroll 4
    for (int k = 0; k < 16; ++k) {
      int n = ip[k];
      float dx = px - pb[n*3+0], dy = py - pb[n*3+1], dz = pz - pb[n*3+2];
      s += (dx*dx + dy*dy) + dz*dz;
    }
  }
  out[e] = s * 0.0625f;
}

__global__ void hbar_kernel(const float* __restrict__ x, const float* __restrict__ pos,
                            const int* __restrict__ idx, int Mlvl, int C, int B,
                            float* __restrict__ out)
{
  hbar_body(x, pos, idx, Mlvl, C, B, out, blockIdx.x * 256 + threadIdx.x);
}

// ------------------------------------------------------------------
// Fused dispatch 1 (512 threads): fps1 (blocks 0-1) || knn0 (2..513) || pack pp0.
// All parts depend ONLY on inputs (pos). fps blocks dispatch first. Static LDS
// 128KB+ => 1 block/CU for every block: fps owns its CUs exclusively.
__global__ __launch_bounds__(512, 1) void fused1_kernel(const float* __restrict__ pos,
    int* __restrict__ idx1, float* __restrict__ pos1, float4* __restrict__ pp1,
    float4* __restrict__ pp0, int* __restrict__ knn0)
{
  __shared__ __align__(16) char sm[8192 * 16 + 128];
  const int blk = blockIdx.x;
  if (blk < 2) {
    fps_body<8192, 4096, 512>(pos + (size_t)blk * 8192 * 3,
                              idx1 + (size_t)blk * 4096,
                              pos1 + (size_t)blk * 4096 * 3,
                              pp1 + (size_t)blk * 4096,
                              (float4*)sm, (u64*)(sm + 8192 * 16));
  } else if (blk < 514) {
    const int i = blk - 2;
    knn_body<512, 16>(pos, 8192, knn0, (float4*)sm, i & 255, i >> 8);
  } else {
    const int i = (blk - 514) * 512 + threadIdx.x;
    if (i < 2 * 8192) {
      float x = pos[i*3+0], y = pos[i*3+1], z = pos[i*3+2];
      pp0[i] = make_float4(x, y, z, (x*x + y*y) + z*z);
    }
  }
}

// Fused dispatch 2 (512 threads): fps2 (0-1) || knn1 (2..257) || hbar0 (258..513)
// || three_nn0 (514..1025). Inputs are fused1 products only — no intra-deps.
// LDS padded to 84KB => 1 block/CU: fps2 owns its CUs (R8 hazard fix).
__global__ __launch_bounds__(512, 1) void fused2_kernel(const float* __restrict__ pos,
    const float* __restrict__ pos1, const float* __restrict__ x,
    const int* __restrict__ knn0, float* __restrict__ hbar,
    int* __restrict__ idx2, float* __restrict__ pos2, float4* __restrict__ pp2,
    int* __restrict__ knn1,
    const float4* __restrict__ pp0, const float4* __restrict__ pp1,
    int* __restrict__ nn0i, float* __restrict__ nn0w)
{
  __shared__ __align__(16) char sm[84000];
  const int blk = blockIdx.x;
  if (blk < 2) {
    fps_body<4096, 2048, 512>(pos1 + (size_t)blk * 4096 * 3,
                              idx2 + (size_t)blk * 2048,
                              pos2 + (size_t)blk * 2048 * 3,
                              pp2 + (size_t)blk * 2048,
                              (float4*)sm, (u64*)(sm + 4096 * 16));
  } else if (blk < 258) {
    const int i = blk - 2;
    knn_body<512, 16>(pos1, 4096, knn1, (float4*)sm, i & 127, i >> 7);
  } else if (blk < 514) {
    const int e = (blk - 258) * 512 + threadIdx.x;
    hbar_body(x, pos, knn0, 8192, 4, 2, hbar, e);
  } else {
    const int i = blk - 514;
    three_nn_body<512, 16>(pp0, pp1, 8192, 4096, nn0i, nn0w, (float4*)sm, i & 255, i >> 8);
  }
}

// ------------------------------------------------------------------
__global__ void interp_kernel(const float* __restrict__ f, const int* __restrict__ nidx,
                              const float* __restrict__ nw, int Mq, int Msub, int C, int B,
                              float* __restrict__ out)
{
  const int tot = B * Mq * C;
  int e = blockIdx.x * 256 + threadIdx.x;
  if (e >= tot) return;
  const int c = e % C;
  const int p = e / C;
  const int b = p / Mq;
  const float* fb = f + (size_t)b * Msub * C;
  const int* ip   = nidx + (size_t)p * 3;
  const float* wp = nw   + (size_t)p * 3;
  out[e] = (wp[0] * fb[(size_t)ip[0]*C + c] + wp[1] * fb[(size_t)ip[1]*C + c])
         +  wp[2] * fb[(size_t)ip[2]*C + c];
}

// ------------------------------------------------------------------
__global__ void gather_kernel(const float* __restrict__ src, const int* __restrict__ idx,
                              int Mq, int Msrc, int C, int B, float* __restrict__ dst)
{
  const int tot = B * Mq * C;
  int e = blockIdx.x * 256 + threadIdx.x;
  if (e >= tot) return;
  const int c = e % C;
  const int p = e / C;
  const int b = p / Mq;
  dst[e] = src[((size_t)b * Msrc + idx[p]) * C + c];
}

// ------------------------------------------------------------------
// Fused GEMM: out[M,F] = act( A[M,Ka]@W1[Ka,F] + B2[M,Kb]@W2[Kb,F] + bias )
__global__ __launch_bounds__(256) void gemm_kernel(const float* __restrict__ A, int Ka,
                                                   const float* __restrict__ B2, int Kb,
                                                   const float* __restrict__ W1,
                                                   const float* __restrict__ W2,
                                                   const float* __restrict__ bias,
                                                   float* __restrict__ out,
                                                   int M, int F, int act)
{
  __shared__ __align__(16) float As[16][64];
  __shared__ __align__(16) float Ws[16][64];
  const int tid  = threadIdx.x;
  const int row0 = blockIdx.x * 64;
  const int col0 = blockIdx.y * 64;
  const int tx = tid & 15, ty = tid >> 4;
  const int K = Ka + Kb;
  float acc[4][4] = {};
  for (int k0 = 0; k0 < K; k0 += 16) {
#pragma unroll
    for (int i = 0; i < 4; ++i) {
      int e = tid + i * 256;
      int m = e & 63, kk = e >> 6;
      int k = k0 + kk;
      float v = 0.f;
      if (k < Ka)     v = A [(size_t)(row0 + m) * Ka + k];
      else if (k < K) v = B2[(size_t)(row0 + m) * Kb + (k - Ka)];
      As[kk][m] = v;
      float wv = 0.f;
      if (k < Ka)     wv = W1[(size_t)k * F + col0 + m];
      else if (k < K) wv = W2[(size_t)(k - Ka) * F + col0 + m];
      Ws[kk][m] = wv;
    }
    __syncthreads();
#pragma unroll
    for (int kk = 0; kk < 16; ++kk) {
      const float4 a4 = *reinterpret_cast<const float4*>(&As[kk][ty * 4]);
      const float4 b4 = *reinterpret_cast<const float4*>(&Ws[kk][tx * 4]);
      const float av[4] = {a4.x, a4.y, a4.z, a4.w};
      const float bv[4] = {b4.x, b4.y, b4.z, b4.w};
#pragma unroll
      for (int i2 = 0; i2 < 4; ++i2)
#pragma unroll
        for (int j2 = 0; j2 < 4; ++j2)
          acc[i2][j2] = fmaf(av[i2], bv[j2], acc[i2][j2]);
    }
    __syncthreads();
  }
#pragma unroll
  for (int i2 = 0; i2 < 4; ++i2) {
    int r = row0 + ty * 4 + i2;
#pragma unroll
    for (int j2 = 0; j2 < 4; ++j2) {
      int cc = col0 + tx * 4 + j2;
      float v = acc[i2][j2];
      if (bias) v += bias[cc];
      if (act)  v = leakyf(v);
      out[(size_t)r * F + cc] = v;
    }
  }
}

// ------------------------------------------------------------------
extern "C" void kernel_launch(void* const* d_in, const int* in_sizes, int n_in,
                              void* d_out, int out_size, void* d_ws, size_t ws_size,
                              hipStream_t stream)
{
  (void)in_sizes; (void)n_in; (void)out_size; (void)ws_size;
  const float* x          = (const float*)d_in[0];   // [2,8192,4]
  const float* pos        = (const float*)d_in[1];   // [2,8192,3]
  const float* w_self0    = (const float*)d_in[2];   // [4,64]
  const float* w_edge0    = (const float*)d_in[3];   // [8,64]
  const float* w_self1    = (const float*)d_in[4];   // [64,128]
  const float* w_edge1    = (const float*)d_in[5];   // [68,128]
  const float* w_self2    = (const float*)d_in[6];   // [128,256]
  const float* w_edge2    = (const float*)d_in[7];   // [132,256]
  const float* w_up1      = (const float*)d_in[8];   // [384,128]
  const float* b_up1      = (const float*)d_in[9];   // [128]
  const float* w_upc1s    = (const float*)d_in[10];  // [128,128]
  const float* w_upc1e    = (const float*)d_in[11];  // [132,128]
  const float* w_up0      = (const float*)d_in[12];  // [192,64]
  const float* b_up0      = (const float*)d_in[13];  // [64]
  const float* w_upc0s    = (const float*)d_in[14];  // [64,64]
  const float* w_upc0e    = (const float*)d_in[15];  // [68,64]
  const float* w_out      = (const float*)d_in[16];  // [64,128]
  const float* b_out      = (const float*)d_in[17];  // [128]
  float* out = (float*)d_out;                        // [2,8192,128]

  char* ws = (char*)d_ws;
  size_t off = 0;
  auto alloc = [&](size_t nbytes) -> void* {
    off = (off + 255) & ~(size_t)255;
    void* p = ws + off;
    off += nbytes;
    return p;
  };
  int*    knn0   = (int*)   alloc((size_t)2*8192*16*4);
  int*    knn1   = (int*)   alloc((size_t)2*4096*16*4);
  int*    knn2   = (int*)   alloc((size_t)2*2048*16*4);
  int*    idx1   = (int*)   alloc((size_t)2*4096*4);
  int*    idx2   = (int*)   alloc((size_t)2*2048*4);
  float*  pos1   = (float*) alloc((size_t)2*4096*3*4);
  float*  pos2   = (float*) alloc((size_t)2*2048*3*4);
  float4* pp0    = (float4*)alloc((size_t)2*8192*16);
  float4* pp1    = (float4*)alloc((size_t)2*4096*16);
  float4* pp2    = (float4*)alloc((size_t)2*2048*16);
  float*  feat0  = (float*) alloc((size_t)2*8192*64*4);
  float*  feat0g = (float*) alloc((size_t)2*4096*64*4);
  float*  feat1  = (float*) alloc((size_t)2*4096*128*4);
  float*  feat1g = (float*) alloc((size_t)2*2048*128*4);
  float*  feat2  = (float*) alloc((size_t)2*2048*256*4);
  int*    nn1i   = (int*)   alloc((size_t)2*4096*3*4);
  float*  nn1w   = (float*) alloc((size_t)2*4096*3*4);
  int*    nn0i   = (int*)   alloc((size_t)2*8192*3*4);
  float*  nn0w   = (float*) alloc((size_t)2*8192*3*4);
  float*  interp = (float*) alloc((size_t)2*4096*256*4);  // reused for interp0 (same size)
  float*  hbar   = (float*) alloc((size_t)2*8192*68*4);   // max of all hbar stages
  float*  fupa   = (float*) alloc((size_t)2*4096*128*4);  // fup1a, later fup0a (same size)
  float*  fup1   = (float*) alloc((size_t)2*4096*128*4);
  float*  fout   = (float*) alloc((size_t)2*8192*64*4);

  // D1: fps1 || knn0 || pack(pp0)   (2 + 512 + 32 blocks)
  fused1_kernel<<<546, 512, 0, stream>>>(pos, idx1, pos1, pp1, pp0, knn0);
  // D2: fps2 || knn1 || hbar0 || three_nn0   (2 + 256 + 256 + 512 blocks)
  fused2_kernel<<<1026, 512, 0, stream>>>(pos, pos1, x, knn0, hbar,
                                          idx2, pos2, pp2, knn1, pp0, pp1, nn0i, nn0w);
  // level-0 edge conv finish
  gemm_kernel<<<dim3(256, 1), 256, 0, stream>>>(x, 4, hbar, 8, w_self0, w_edge0, nullptr,
                                                feat0, 16384, 64, 1);
  // level-1 chain
  gather_kernel<<<2048, 256, 0, stream>>>(feat0, idx1, 4096, 8192, 64, 2, feat0g);
  hbar_kernel<<<2176, 256, 0, stream>>>(feat0g, pos1, knn1, 4096, 64, 2, hbar);
  gemm_kernel<<<dim3(128, 2), 256, 0, stream>>>(feat0g, 64, hbar, 68, w_self1, w_edge1, nullptr,
                                                feat1, 8192, 128, 1);
  // level-2 chain
  gather_kernel<<<2048, 256, 0, stream>>>(feat1, idx2, 2048, 4096, 128, 2, feat1g);
  knn_kernel<<<dim3(128, 2), 256, 0, stream>>>(pos2, 2048, knn2);
  hbar_kernel<<<2112, 256, 0, stream>>>(feat1g, pos2, knn2, 2048, 128, 2, hbar);
  gemm_kernel<<<dim3(64, 4), 256, 0, stream>>>(feat1g, 128, hbar, 132, w_self2, w_edge2, nullptr,
                                               feat2, 4096, 256, 1);
  // up level 1
  three_nn_kernel<<<dim3(256, 2), 256, 0, stream>>>(pp1, pp2, 4096, 2048, nn1i, nn1w);
  interp_kernel<<<8192, 256, 0, stream>>>(feat2, nn1i, nn1w, 4096, 2048, 256, 2, interp);
  gemm_kernel<<<dim3(128, 2), 256, 0, stream>>>(interp, 256, feat1, 128,
                                                w_up1, w_up1 + (size_t)256 * 128, b_up1,
                                                fupa, 8192, 128, 1);
  hbar_kernel<<<4224, 256, 0, stream>>>(fupa, pos1, knn1, 4096, 128, 2, hbar);
  gemm_kernel<<<dim3(128, 2), 256, 0, stream>>>(fupa, 128, hbar, 132, w_upc1s, w_upc1e, nullptr,
                                                fup1, 8192, 128, 1);
  // up level 0 (nn0i/nn0w already computed in fused2)
  interp_kernel<<<8192, 256, 0, stream>>>(fup1, nn0i, nn0w, 8192, 4096, 128, 2, interp);
  gemm_kernel<<<dim3(256, 1), 256, 0, stream>>>(interp, 128, feat0, 64,
                                                w_up0, w_up0 + (size_t)128 * 64, b_up0,
                                                fupa, 16384, 64, 1);
  hbar_kernel<<<4352, 256, 0, stream>>>(fupa, pos, knn0, 8192, 64, 2, hbar);
  gemm_kernel<<<dim3(256, 1), 256, 0, stream>>>(fupa, 64, hbar, 68, w_upc0s, w_upc0e, nullptr,
                                                fout, 16384, 64, 1);
  // final projection
  gemm_kernel<<<dim3(256, 2), 256, 0, stream>>>(fout, 64, nullptr, 0, w_out, nullptr, b_out,
                                                out, 16384, 128, 0);
}